// Round 10
// baseline (541.105 us; speedup 1.0000x reference)
//
#include <hip/hip_runtime.h>
#include <math.h>

// Swin block: B=8, C=256, H=W=128, WS=8, SS=4, NH=8, dh=32
// Weights frag-packed: wf[((tile*KT+kt)*64+l)*8+e] = W[tile*16+(l&15)][kt*32+(l>>4)*8+e]
// attn: x read once (reg stash), XCD swizzle. mlp: barrier-free wave-private-m pipeline.

#define LDH 264   // bf16 row stride for [64][256] tiles (attn)
#define LDS_S 40  // per-wave q/k slots [64][40]
#define LDVT 72   // vT [32][72]

typedef __attribute__((ext_vector_type(8))) short bf16x8;
typedef __attribute__((ext_vector_type(4))) short bf16x4;
typedef __attribute__((ext_vector_type(4))) float f32x4;

#define WF(wf, tile, KT, kt, ln) (*(const bf16x8*)&(wf)[((((tile)*(KT)) + (kt))*64 + (ln))*8])

static __device__ __forceinline__ float bf2f(short s){
  union { unsigned u; float f; } cv;
  cv.u = ((unsigned)(unsigned short)s) << 16;
  return cv.f;
}
static __device__ __forceinline__ short f2bf(float f){
  union { float f; unsigned u; } cv; cv.f = f;
  unsigned r = (cv.u + 0x7FFFu + ((cv.u >> 16) & 1u)) >> 16;  // RNE
  return (short)r;
}
static __device__ __forceinline__ float gelu_f(float x){
  return 0.5f * x * (1.0f + erff(x * 0.7071067811865475f));
}

// ---------------- K0: fp32 -> bf16 fragment-order repack ----------------
__global__ void wpack_kernel(const float* __restrict__ src, short* __restrict__ dst,
                             int K){
  const int t8 = blockIdx.x * 256 + threadIdx.x;
  const int e0 = t8 * 8;
  const int l   = (e0 >> 3) & 63;
  const int blk = e0 >> 9;
  const int KT  = K >> 5;
  const int kt   = blk % KT;
  const int tile = blk / KT;
  const int row = tile*16 + (l & 15);
  const int kb  = kt*32 + (l >> 4)*8;
  const float* s = src + row*K + kb;
  bf16x8 o;
  #pragma unroll
  for (int e=0;e<8;++e) o[e] = f2bf(s[e]);
  *(bf16x8*)&dst[e0] = o;
}

// ---------------- kernel 1: LN1 + QKV + attention + out-proj(swapped) -> win2T ----------------
#define K1_OFF_WV  33792
#define K1_OFF_RED 74752
#define K1_SMEM    76800

__global__ __launch_bounds__(256, 2)
void swin_attn_kernel(const float* __restrict__ x,
                      const float* __restrict__ ln1w, const float* __restrict__ ln1b,
                      const float* __restrict__ inb,  const float* __restrict__ outb,
                      const short* __restrict__ wqkv, const short* __restrict__ wout,
                      short* __restrict__ win2T)
{
  __shared__ char smem[K1_SMEM];
  short* sh_h   = (short*)smem;
  short* xsh    = (short*)(smem + K1_OFF_WV);   // x bf16 stash (post-attention)
  float* red_s  = (float*)(smem + K1_OFF_RED);
  float* red_q2 = red_s + 256;

  const int tid = threadIdx.x;
  const int wv  = tid >> 6;
  const int ln  = tid & 63;
  const int rowa = ln & 15;
  const int kg   = ln >> 4;

  short* slotA = (short*)(smem + K1_OFF_WV) + wv*5120;
  short* slotB = slotA + 2560;

  const int bid = blockIdx.x;
  const int wi  = ((bid & 7) << 8) | (bid >> 3);   // XCD swizzle (2048%8==0, bijective)
  const int b  = wi >> 8;
  const int wh = (wi >> 4) & 15;
  const int ww = wi & 15;

  const int hh = (wh*8 + (ln >> 3) + 4) & 127;
  const int wc = (ww*8 + (ln & 7) + 4) & 127;
  const int offhw = hh*128 + wc;
  const int xbase = b << 22;

  unsigned xpk[32];
  {
    const int cbeg = wv*64;
    float vals[64];
    float s = 0.f, sq = 0.f;
    #pragma unroll
    for (int j = 0; j < 64; ++j){
      float v = x[xbase + ((cbeg + j) << 14) + offhw];
      vals[j] = v; s += v; sq += v*v;
    }
    #pragma unroll
    for (int p = 0; p < 32; ++p){
      const unsigned lo = (unsigned)(unsigned short)f2bf(vals[2*p]);
      const unsigned hi = (unsigned)(unsigned short)f2bf(vals[2*p+1]);
      xpk[p] = lo | (hi << 16);
    }
    red_s[cbeg + ln]  = s;
    red_q2[cbeg + ln] = sq;
    __syncthreads();
    float sum = red_s[ln] + red_s[64+ln] + red_s[128+ln] + red_s[192+ln];
    float ssq = red_q2[ln] + red_q2[64+ln] + red_q2[128+ln] + red_q2[192+ln];
    float mean = sum * 0.00390625f;
    float var  = ssq * 0.00390625f - mean*mean;
    float rstd = rsqrtf(var + 1e-5f);
    #pragma unroll
    for (int j = 0; j < 64; ++j){
      const int c = cbeg + j;
      sh_h[ln*LDH + c] = f2bf((vals[j] - mean) * rstd * ln1w[c] + ln1b[c]);
    }
  }
  __syncthreads();

  const float scale = 0.1767766952966369f;
  f32x4 oacc[4][4];
  #pragma unroll
  for (int mt=0;mt<4;++mt)
    #pragma unroll
    for (int j=0;j<4;++j)
      oacc[mt][j] = (f32x4){0.f,0.f,0.f,0.f};

  #pragma unroll
  for (int hd = 0; hd < 2; ++hd){
    const int hc = (2*wv + hd) * 32;
    const int tq = (2*wv + hd) * 2;

    {
      f32x4 aq[4][2], ak[4][2];
      #pragma unroll
      for (int mt=0;mt<4;++mt){
        aq[mt][0]=(f32x4){0,0,0,0}; aq[mt][1]=(f32x4){0,0,0,0};
        ak[mt][0]=(f32x4){0,0,0,0}; ak[mt][1]=(f32x4){0,0,0,0};
      }
      #pragma unroll
      for (int kt=0;kt<8;++kt){
        bf16x8 av[4], bq[2], bk[2];
        #pragma unroll
        for (int mt=0;mt<4;++mt)
          av[mt] = *(const bf16x8*)&sh_h[(mt*16+rowa)*LDH + kt*32 + kg*8];
        #pragma unroll
        for (int nt=0;nt<2;++nt){
          bq[nt] = WF(wqkv, tq + nt,      8, kt, ln);
          bk[nt] = WF(wqkv, 16 + tq + nt, 8, kt, ln);
        }
        #pragma unroll
        for (int mt=0;mt<4;++mt)
          #pragma unroll
          for (int nt=0;nt<2;++nt){
            aq[mt][nt] = __builtin_amdgcn_mfma_f32_16x16x32_bf16(av[mt], bq[nt], aq[mt][nt], 0, 0, 0);
            ak[mt][nt] = __builtin_amdgcn_mfma_f32_16x16x32_bf16(av[mt], bk[nt], ak[mt][nt], 0, 0, 0);
          }
      }
      #pragma unroll
      for (int nt=0;nt<2;++nt){
        const float biasq = inb[hc + nt*16 + rowa];
        const float biask = inb[256 + hc + nt*16 + rowa];
        #pragma unroll
        for (int mt=0;mt<4;++mt)
          #pragma unroll
          for (int i=0;i<4;++i){
            slotA[(mt*16 + kg*4 + i)*LDS_S + nt*16 + rowa] = f2bf(aq[mt][nt][i] + biasq);
            slotB[(mt*16 + kg*4 + i)*LDS_S + nt*16 + rowa] = f2bf(ak[mt][nt][i] + biask);
          }
      }
    }

    f32x4 sacc[4][4];
    #pragma unroll
    for (int mt=0;mt<4;++mt)
      #pragma unroll
      for (int nt=0;nt<4;++nt)
        sacc[mt][nt] = (f32x4){0.f,0.f,0.f,0.f};
    {
      bf16x8 aq[4], bk[4];
      #pragma unroll
      for (int mt=0;mt<4;++mt)
        aq[mt] = *(const bf16x8*)&slotA[(mt*16+rowa)*LDS_S + kg*8];
      #pragma unroll
      for (int nt=0;nt<4;++nt)
        bk[nt] = *(const bf16x8*)&slotB[(nt*16+rowa)*LDS_S + kg*8];
      __builtin_amdgcn_s_setprio(1);
      #pragma unroll
      for (int mt=0;mt<4;++mt)
        #pragma unroll
        for (int nt=0;nt<4;++nt)
          sacc[mt][nt] = __builtin_amdgcn_mfma_f32_16x16x32_bf16(aq[mt], bk[nt], sacc[mt][nt], 0, 0, 0);
      __builtin_amdgcn_s_setprio(0);
    }

    {
      f32x4 accv[4][2];
      #pragma unroll
      for (int mt=0;mt<4;++mt){ accv[mt][0]=(f32x4){0,0,0,0}; accv[mt][1]=(f32x4){0,0,0,0}; }
      #pragma unroll
      for (int kt=0;kt<8;++kt){
        bf16x8 av[4], bw[2];
        #pragma unroll
        for (int mt=0;mt<4;++mt)
          av[mt] = *(const bf16x8*)&sh_h[(mt*16+rowa)*LDH + kt*32 + kg*8];
        #pragma unroll
        for (int nt=0;nt<2;++nt)
          bw[nt] = WF(wqkv, 32 + tq + nt, 8, kt, ln);
        #pragma unroll
        for (int mt=0;mt<4;++mt)
          #pragma unroll
          for (int nt=0;nt<2;++nt)
            accv[mt][nt] = __builtin_amdgcn_mfma_f32_16x16x32_bf16(av[mt], bw[nt], accv[mt][nt], 0, 0, 0);
      }
      #pragma unroll
      for (int nt=0;nt<2;++nt){
        const float bias = inb[512 + hc + nt*16 + rowa];
        #pragma unroll
        for (int mt=0;mt<4;++mt)
          #pragma unroll
          for (int i=0;i<4;++i)
            slotB[(nt*16 + rowa)*LDVT + mt*16 + kg*4 + i] = f2bf(accv[mt][nt][i] + bias);
      }
    }

    #pragma unroll
    for (int mt=0;mt<4;++mt){
      #pragma unroll
      for (int i=0;i<4;++i){
        float v0 = sacc[mt][0][i]*scale;
        float v1 = sacc[mt][1][i]*scale;
        float v2 = sacc[mt][2][i]*scale;
        float v3 = sacc[mt][3][i]*scale;
        float mx = fmaxf(fmaxf(v0,v1), fmaxf(v2,v3));
        #pragma unroll
        for (int d=1; d<16; d<<=1) mx = fmaxf(mx, __shfl_xor(mx, d, 64));
        v0 = __expf(v0-mx); v1 = __expf(v1-mx); v2 = __expf(v2-mx); v3 = __expf(v3-mx);
        float sm = v0+v1+v2+v3;
        #pragma unroll
        for (int d=1; d<16; d<<=1) sm += __shfl_xor(sm, d, 64);
        const float inv = 1.f / sm;
        sacc[mt][0][i] = v0*inv; sacc[mt][1][i] = v1*inv;
        sacc[mt][2][i] = v2*inv; sacc[mt][3][i] = v3*inv;
      }
    }

    #pragma unroll
    for (int ck=0; ck<2; ++ck){
      #pragma unroll
      for (int ntl=0; ntl<2; ++ntl)
        #pragma unroll
        for (int mt=0;mt<4;++mt)
          #pragma unroll
          for (int i=0;i<4;++i)
            slotA[(mt*16 + kg*4 + i)*LDS_S + ntl*16 + rowa] = f2bf(sacc[mt][2*ck+ntl][i]);
      bf16x8 ap[4], bv[2];
      #pragma unroll
      for (int mt=0;mt<4;++mt)
        ap[mt] = *(const bf16x8*)&slotA[(mt*16+rowa)*LDS_S + kg*8];
      #pragma unroll
      for (int nt=0;nt<2;++nt)
        bv[nt] = *(const bf16x8*)&slotB[(nt*16+rowa)*LDVT + ck*32 + kg*8];
      __builtin_amdgcn_s_setprio(1);
      #pragma unroll
      for (int mt=0;mt<4;++mt)
        #pragma unroll
        for (int nt=0;nt<2;++nt)
          oacc[mt][hd*2+nt] = __builtin_amdgcn_mfma_f32_16x16x32_bf16(ap[mt], bv[nt], oacc[mt][hd*2+nt], 0, 0, 0);
      __builtin_amdgcn_s_setprio(0);
    }
  }

  __syncthreads();

  #pragma unroll
  for (int j=0;j<4;++j){
    const int col = wv*64 + j*16 + rowa;
    #pragma unroll
    for (int mt=0;mt<4;++mt)
      #pragma unroll
      for (int i=0;i<4;++i)
        sh_h[(mt*16 + kg*4 + i)*LDH + col] = f2bf(oacc[mt][j][i]);
  }
  {
    const int cbeg = wv*64;
    #pragma unroll
    for (int q=0;q<8;++q){
      bf16x8 pk;
      #pragma unroll
      for (int e=0;e<4;++e){
        const unsigned w = xpk[q*4+e];
        pk[2*e]   = (short)(w & 0xffffu);
        pk[2*e+1] = (short)(w >> 16);
      }
      *(bf16x8*)&xsh[ln*LDH + cbeg + q*8] = pk;
    }
  }
  __syncthreads();

  {
    f32x4 acc[4][4];
    #pragma unroll
    for (int c0=0;c0<4;++c0)
      #pragma unroll
      for (int t0=0;t0<4;++t0)
        acc[c0][t0] = (f32x4){0.f,0.f,0.f,0.f};
    for (int kt=0; kt<8; ++kt){
      bf16x8 aw[4], bo[4];
      #pragma unroll
      for (int c0=0;c0<4;++c0)
        aw[c0] = WF(wout, wv*4 + c0, 8, kt, ln);
      #pragma unroll
      for (int t0=0;t0<4;++t0)
        bo[t0] = *(const bf16x8*)&sh_h[(t0*16+rowa)*LDH + kt*32 + kg*8];
      #pragma unroll
      for (int c0=0;c0<4;++c0)
        #pragma unroll
        for (int t0=0;t0<4;++t0)
          acc[c0][t0] = __builtin_amdgcn_mfma_f32_16x16x32_bf16(aw[c0], bo[t0], acc[c0][t0], 0, 0, 0);
    }
    #pragma unroll
    for (int c0=0;c0<4;++c0){
      #pragma unroll
      for (int i=0;i<4;++i){
        const int ch = wv*64 + c0*16 + kg*4 + i;
        const float bias = outb[ch];
        #pragma unroll
        for (int t0=0;t0<4;++t0){
          const int tok = t0*16 + rowa;
          const float res = bf2f(xsh[tok*LDH + ch]);
          win2T[(wi<<14) + ch*64 + tok] = f2bf(acc[c0][t0][i] + bias + res);
        }
      }
    }
  }
}

// ---------------- kernel 2: LN2 + barrier-free MLP (wave = token-slice) ----------------
// LDS (34816 B): Yf frag-packed h2 [4 ttile][8 kt][64 lane][8] (32768) + red 2048.
// Wave wv owns tokens wv*16..+15. m never leaves the wave (shfl handoff GEMM1->GEMM2).
// Raw s_barrier per chunk = convoy only (no data dependence) -> keeps L1 weight sharing.
#define K2_SMEM  34816

__global__ __launch_bounds__(256, 2)
void swin_mlp_kernel(const short* __restrict__ win2T,
                     const float* __restrict__ ln2w, const float* __restrict__ ln2b,
                     const float* __restrict__ b1,   const float* __restrict__ b2,
                     const short* __restrict__ w1,   const short* __restrict__ w2,
                     float* __restrict__ out)
{
  __shared__ char smem[K2_SMEM];
  short* Yf = (short*)smem;                 // ((ttile*8+kt)*64 + l)*8 + e
  float* red_s  = (float*)(smem + 32768);
  float* red_q2 = red_s + 256;

  const int tid = threadIdx.x;
  const int wv  = tid >> 6;
  const int ln  = tid & 63;
  const int rowa = ln & 15;
  const int kg   = ln >> 4;

  const int bid = blockIdx.x;
  const int wi  = ((bid & 7) << 8) | (bid >> 3);   // same XCD swizzle as attn (L2 affinity)
  const int wb = wi << 14;

  // ---- LN2: thread (wv,ln) = token ln, ch slice wv*64..; write h2 frag-packed ----
  {
    float vals[64];
    float s = 0.f, sq = 0.f;
    const int cbeg = wv*64;
    #pragma unroll
    for (int j=0;j<64;++j){
      float v = bf2f(win2T[wb + (cbeg + j)*64 + ln]);
      vals[j] = v; s += v; sq += v*v;
    }
    red_s[cbeg + ln]  = s;
    red_q2[cbeg + ln] = sq;
    __syncthreads();
    float sum = red_s[ln] + red_s[64+ln] + red_s[128+ln] + red_s[192+ln];
    float ssq = red_q2[ln] + red_q2[64+ln] + red_q2[128+ln] + red_q2[192+ln];
    float mean = sum * 0.00390625f;
    float var  = ssq * 0.00390625f - mean*mean;
    float rstd = rsqrtf(var + 1e-5f);
    const int ttile = ln >> 4;
    #pragma unroll
    for (int kl=0;kl<2;++kl){          // kt = wv*2 + kl
      const int kt = wv*2 + kl;
      #pragma unroll
      for (int kgw=0;kgw<4;++kgw){
        bf16x8 pkv;
        #pragma unroll
        for (int e=0;e<8;++e){
          const int j = kl*32 + kgw*8 + e;
          const int c = cbeg + j;
          pkv[e] = f2bf((vals[j] - mean) * rstd * ln2w[c] + ln2b[c]);
        }
        *(bf16x8*)&Yf[(((ttile*8 + kt)*64) + kgw*16 + (ln & 15))*8] = pkv;
      }
    }
  }
  __syncthreads();   // Yf published (only true barrier in the kernel)

  // ---- per-wave pipeline: 8 chunks x {GEMM1(128 hid x 16 tok) -> gelu/pack -> GEMM2} ----
  f32x4 acc2[16];    // D'[ch tile 0..15][tok 16] for wave's tokens
  #pragma unroll
  for (int t=0;t<16;++t) acc2[t] = (f32x4){0.f,0.f,0.f,0.f};

  const int s0 = ((kg & 1) << 5) + rowa;   // shfl src lane base: 2*(kg&1)*16 + rowa

  for (int chk = 0; chk < 8; ++chk){
    // GEMM1: acc1[t] = w1-tile(chk*8+t) x Y(tokens of this wave)
    f32x4 acc1[8];
    #pragma unroll
    for (int t=0;t<8;++t) acc1[t] = (f32x4){0.f,0.f,0.f,0.f};
    #pragma unroll
    for (int kt=0;kt<8;++kt){
      const bf16x8 bh = *(const bf16x8*)&Yf[(((wv*8 + kt)*64) + ln)*8];
      bf16x8 aw[8];
      #pragma unroll
      for (int t=0;t<8;++t)
        aw[t] = WF(w1, chk*8 + t, 8, kt, ln);
      __builtin_amdgcn_s_setprio(1);
      #pragma unroll
      for (int t=0;t<8;++t)
        acc1[t] = __builtin_amdgcn_mfma_f32_16x16x32_bf16(aw[t], bh, acc1[t], 0, 0, 0);
      __builtin_amdgcn_s_setprio(0);
    }

    // gelu + bias -> packed bf16 pairs (hid-local kg*4+{2j,2j+1} per dword)
    unsigned pk[8][2];
    #pragma unroll
    for (int t=0;t<8;++t){
      const int hb = chk*128 + t*16 + kg*4;
      const f32x4 b1v = *(const f32x4*)&b1[hb];
      const unsigned g0 = (unsigned)(unsigned short)f2bf(gelu_f(acc1[t][0] + b1v[0]));
      const unsigned g1 = (unsigned)(unsigned short)f2bf(gelu_f(acc1[t][1] + b1v[1]));
      const unsigned g2 = (unsigned)(unsigned short)f2bf(gelu_f(acc1[t][2] + b1v[2]));
      const unsigned g3 = (unsigned)(unsigned short)f2bf(gelu_f(acc1[t][3] + b1v[3]));
      pk[t][0] = g0 | (g1 << 16);
      pk[t][1] = g2 | (g3 << 16);
    }

    // GEMM2: acc2[t] += w2-tile(t) x m ; B-frag built from pk via shfl
    #pragma unroll
    for (int kt2=0;kt2<4;++kt2){
      const unsigned a0 = pk[2*kt2][0],   a1 = pk[2*kt2][1];
      const unsigned c0 = pk[2*kt2+1][0], c1 = pk[2*kt2+1][1];
      const unsigned p00 = (unsigned)__shfl((int)a0, s0);
      const unsigned p01 = (unsigned)__shfl((int)a1, s0);
      const unsigned p02 = (unsigned)__shfl((int)a0, s0+16);
      const unsigned p03 = (unsigned)__shfl((int)a1, s0+16);
      const unsigned q00 = (unsigned)__shfl((int)c0, s0);
      const unsigned q01 = (unsigned)__shfl((int)c1, s0);
      const unsigned q02 = (unsigned)__shfl((int)c0, s0+16);
      const unsigned q03 = (unsigned)__shfl((int)c1, s0+16);
      union { unsigned u[4]; bf16x8 v; } bm;
      const bool hi = (kg & 2) != 0;
      bm.u[0] = hi ? q00 : p00;
      bm.u[1] = hi ? q01 : p01;
      bm.u[2] = hi ? q02 : p02;
      bm.u[3] = hi ? q03 : p03;
      bf16x8 aw2[16];
      #pragma unroll
      for (int t=0;t<16;++t)
        aw2[t] = WF(w2, t, 32, chk*4 + kt2, ln);
      __builtin_amdgcn_s_setprio(1);
      #pragma unroll
      for (int t=0;t<16;++t)
        acc2[t] = __builtin_amdgcn_mfma_f32_16x16x32_bf16(aw2[t], bm.v, acc2[t], 0, 0, 0);
      __builtin_amdgcn_s_setprio(0);
    }

    __builtin_amdgcn_s_barrier();   // convoy only (keeps waves' weight streams L1-aligned)
  }

  // ---- epilogue: ch = t*16+kg*4+i, tok = wv*16+rowa; coalesced store + residual ----
  const int b  = wi >> 8;
  const int wh = (wi >> 4) & 15;
  const int ww = wi & 15;
  const int tok = wv*16 + rowa;
  const int r = tok >> 3, cw = tok & 7;
  const int hh = (wh*8 + r + 4) & 127;
  const int wcc = (ww*8 + cw + 4) & 127;
  #pragma unroll
  for (int t=0;t<16;++t){
    #pragma unroll
    for (int i=0;i<4;++i){
      const int ch = t*16 + kg*4 + i;
      float v = acc2[t][i] + b2[ch] + bf2f(win2T[wb + ch*64 + tok]);
      out[(((b<<8) + ch) << 14) + hh*128 + wcc] = v;
    }
  }
}

// ---------------- launch ----------------
extern "C" void kernel_launch(void* const* d_in, const int* in_sizes, int n_in,
                              void* d_out, int out_size, void* d_ws, size_t ws_size,
                              hipStream_t stream) {
  (void)in_sizes; (void)n_in; (void)out_size; (void)ws_size;
  const float* x    = (const float*)d_in[0];
  const float* ln1w = (const float*)d_in[1];
  const float* ln1b = (const float*)d_in[2];
  const float* inw  = (const float*)d_in[3];
  const float* inb  = (const float*)d_in[4];
  const float* outw = (const float*)d_in[5];
  const float* outb = (const float*)d_in[6];
  const float* ln2w = (const float*)d_in[7];
  const float* ln2b = (const float*)d_in[8];
  const float* w1f  = (const float*)d_in[9];
  const float* b1   = (const float*)d_in[10];
  const float* w2f  = (const float*)d_in[11];
  const float* b2   = (const float*)d_in[12];
  float* out = (float*)d_out;

  short* ws    = (short*)d_ws;
  short* wqkv  = ws;            // 768*256   (frag-packed, KT=8)
  short* wout  = ws + 196608;   // 256*256   (frag-packed, KT=8)
  short* w1b   = ws + 262144;   // 1024*256  (frag-packed, KT=8)
  short* w2b   = ws + 524288;   // 256*1024  (frag-packed, KT=32)
  short* win2T = ws + 786432;   // 2048 x 256ch x 64tok bf16

  hipLaunchKernelGGL(wpack_kernel, dim3(96),  dim3(256), 0, stream, inw,  wqkv, 256);
  hipLaunchKernelGGL(wpack_kernel, dim3(32),  dim3(256), 0, stream, outw, wout, 256);
  hipLaunchKernelGGL(wpack_kernel, dim3(128), dim3(256), 0, stream, w1f,  w1b,  256);
  hipLaunchKernelGGL(wpack_kernel, dim3(128), dim3(256), 0, stream, w2f,  w2b,  1024);

  hipLaunchKernelGGL(swin_attn_kernel, dim3(2048), dim3(256), 0, stream,
                     x, ln1w, ln1b, inb, outb, wqkv, wout, win2T);
  hipLaunchKernelGGL(swin_mlp_kernel, dim3(2048), dim3(256), 0, stream,
                     win2T, ln2w, ln2b, b1, b2, w1b, w2b, out);
}

// Round 11
// 512.244 us; speedup vs baseline: 1.0563x; 1.0563x over previous
//
#include <hip/hip_runtime.h>
#include <math.h>

// Swin block: B=8, C=256, H=W=128, WS=8, SS=4, NH=8, dh=32
// Weights frag-packed: wf[((tile*KT+kt)*64+l)*8+e] = W[tile*16+(l&15)][kt*32+(l>>4)*8+e]
// attn: x read once (reg stash), XCD swizzle, frag-packed h. mlp: round-9 lockstep
// pipeline with frag-packed Yf/Mf (conflict-free LDS) + XCD swizzle.

#define LDH 264   // bf16 row stride for row-major [64][256] tiles (o, xsh)
#define LDS_S 40  // per-wave q/k slots [64][40]
#define LDVT 72   // vT [32][72]

typedef __attribute__((ext_vector_type(8))) short bf16x8;
typedef __attribute__((ext_vector_type(4))) short bf16x4;
typedef __attribute__((ext_vector_type(4))) float f32x4;

#define WF(wf, tile, KT, kt, ln) (*(const bf16x8*)&(wf)[((((tile)*(KT)) + (kt))*64 + (ln))*8])
// frag-packed LDS tile (4 token-tiles x KT k-steps): FRAG(base, ttile, KT, kt, lane)
#define FRAG(basep, ttile, KT, kt, l) (*(const bf16x8*)&(basep)[((((ttile)*(KT)) + (kt))*64 + (l))*8])

static __device__ __forceinline__ float bf2f(short s){
  union { unsigned u; float f; } cv;
  cv.u = ((unsigned)(unsigned short)s) << 16;
  return cv.f;
}
static __device__ __forceinline__ short f2bf(float f){
  union { float f; unsigned u; } cv; cv.f = f;
  unsigned r = (cv.u + 0x7FFFu + ((cv.u >> 16) & 1u)) >> 16;  // RNE
  return (short)r;
}
static __device__ __forceinline__ float gelu_f(float x){
  return 0.5f * x * (1.0f + erff(x * 0.7071067811865475f));
}

// ---------------- K0: fp32 -> bf16 fragment-order repack ----------------
__global__ void wpack_kernel(const float* __restrict__ src, short* __restrict__ dst,
                             int K){
  const int t8 = blockIdx.x * 256 + threadIdx.x;
  const int e0 = t8 * 8;
  const int l   = (e0 >> 3) & 63;
  const int blk = e0 >> 9;
  const int KT  = K >> 5;
  const int kt   = blk % KT;
  const int tile = blk / KT;
  const int row = tile*16 + (l & 15);
  const int kb  = kt*32 + (l >> 4)*8;
  const float* s = src + row*K + kb;
  bf16x8 o;
  #pragma unroll
  for (int e=0;e<8;++e) o[e] = f2bf(s[e]);
  *(bf16x8*)&dst[e0] = o;
}

// ---------------- kernel 1: LN1 + QKV + attention + out-proj(swapped) -> win2T ----------------
#define K1_OFF_WV  33792
#define K1_OFF_RED 74752
#define K1_SMEM    76800

__global__ __launch_bounds__(256, 2)
void swin_attn_kernel(const float* __restrict__ x,
                      const float* __restrict__ ln1w, const float* __restrict__ ln1b,
                      const float* __restrict__ inb,  const float* __restrict__ outb,
                      const short* __restrict__ wqkv, const short* __restrict__ wout,
                      short* __restrict__ win2T)
{
  __shared__ char smem[K1_SMEM];
  short* shf    = (short*)smem;                 // h frag-packed (32768 B), then o row-major [64][264]
  short* sh_o   = (short*)smem;
  short* xsh    = (short*)(smem + K1_OFF_WV);   // x bf16 stash row-major (post-attention)
  float* red_s  = (float*)(smem + K1_OFF_RED);
  float* red_q2 = red_s + 256;

  const int tid = threadIdx.x;
  const int wv  = tid >> 6;
  const int ln  = tid & 63;
  const int rowa = ln & 15;
  const int kg   = ln >> 4;

  short* slotA = (short*)(smem + K1_OFF_WV) + wv*5120;
  short* slotB = slotA + 2560;

  const int bid = blockIdx.x;
  const int wi  = ((bid & 7) << 8) | (bid >> 3);   // XCD swizzle (2048%8==0, bijective)
  const int b  = wi >> 8;
  const int wh = (wi >> 4) & 15;
  const int ww = wi & 15;

  const int hh = (wh*8 + (ln >> 3) + 4) & 127;
  const int wc = (ww*8 + (ln & 7) + 4) & 127;
  const int offhw = hh*128 + wc;
  const int xbase = b << 22;

  unsigned xpk[32];
  {
    const int cbeg = wv*64;
    float vals[64];
    float s = 0.f, sq = 0.f;
    #pragma unroll
    for (int j = 0; j < 64; ++j){
      float v = x[xbase + ((cbeg + j) << 14) + offhw];
      vals[j] = v; s += v; sq += v*v;
    }
    #pragma unroll
    for (int p = 0; p < 32; ++p){
      const unsigned lo = (unsigned)(unsigned short)f2bf(vals[2*p]);
      const unsigned hi = (unsigned)(unsigned short)f2bf(vals[2*p+1]);
      xpk[p] = lo | (hi << 16);
    }
    red_s[cbeg + ln]  = s;
    red_q2[cbeg + ln] = sq;
    __syncthreads();
    float sum = red_s[ln] + red_s[64+ln] + red_s[128+ln] + red_s[192+ln];
    float ssq = red_q2[ln] + red_q2[64+ln] + red_q2[128+ln] + red_q2[192+ln];
    float mean = sum * 0.00390625f;
    float var  = ssq * 0.00390625f - mean*mean;
    float rstd = rsqrtf(var + 1e-5f);
    // h frag-packed write: element (tok=ln, ch=cbeg+j) -> [((ttile*8+kt)*64 + kgw*16 + (ln&15))*8 + e]
    const int ttile = ln >> 4;
    #pragma unroll
    for (int kl=0;kl<2;++kl){
      const int kt = wv*2 + kl;
      #pragma unroll
      for (int kgw=0;kgw<4;++kgw){
        bf16x8 pkv;
        #pragma unroll
        for (int e=0;e<8;++e){
          const int j = kl*32 + kgw*8 + e;
          const int c = cbeg + j;
          pkv[e] = f2bf((vals[j] - mean) * rstd * ln1w[c] + ln1b[c]);
        }
        *(bf16x8*)&shf[(((ttile*8 + kt)*64) + kgw*16 + (ln & 15))*8] = pkv;
      }
    }
  }
  __syncthreads();

  const float scale = 0.1767766952966369f;
  f32x4 oacc[4][4];
  #pragma unroll
  for (int mt=0;mt<4;++mt)
    #pragma unroll
    for (int j=0;j<4;++j)
      oacc[mt][j] = (f32x4){0.f,0.f,0.f,0.f};

  #pragma unroll
  for (int hd = 0; hd < 2; ++hd){
    const int hc = (2*wv + hd) * 32;
    const int tq = (2*wv + hd) * 2;

    // ---- q + k fused (shared A-frags from frag-packed h) ----
    {
      f32x4 aq[4][2], ak[4][2];
      #pragma unroll
      for (int mt=0;mt<4;++mt){
        aq[mt][0]=(f32x4){0,0,0,0}; aq[mt][1]=(f32x4){0,0,0,0};
        ak[mt][0]=(f32x4){0,0,0,0}; ak[mt][1]=(f32x4){0,0,0,0};
      }
      #pragma unroll
      for (int kt=0;kt<8;++kt){
        bf16x8 av[4], bq[2], bk[2];
        #pragma unroll
        for (int mt=0;mt<4;++mt)
          av[mt] = FRAG(shf, mt, 8, kt, ln);
        #pragma unroll
        for (int nt=0;nt<2;++nt){
          bq[nt] = WF(wqkv, tq + nt,      8, kt, ln);
          bk[nt] = WF(wqkv, 16 + tq + nt, 8, kt, ln);
        }
        #pragma unroll
        for (int mt=0;mt<4;++mt)
          #pragma unroll
          for (int nt=0;nt<2;++nt){
            aq[mt][nt] = __builtin_amdgcn_mfma_f32_16x16x32_bf16(av[mt], bq[nt], aq[mt][nt], 0, 0, 0);
            ak[mt][nt] = __builtin_amdgcn_mfma_f32_16x16x32_bf16(av[mt], bk[nt], ak[mt][nt], 0, 0, 0);
          }
      }
      #pragma unroll
      for (int nt=0;nt<2;++nt){
        const float biasq = inb[hc + nt*16 + rowa];
        const float biask = inb[256 + hc + nt*16 + rowa];
        #pragma unroll
        for (int mt=0;mt<4;++mt)
          #pragma unroll
          for (int i=0;i<4;++i){
            slotA[(mt*16 + kg*4 + i)*LDS_S + nt*16 + rowa] = f2bf(aq[mt][nt][i] + biasq);
            slotB[(mt*16 + kg*4 + i)*LDS_S + nt*16 + rowa] = f2bf(ak[mt][nt][i] + biask);
          }
      }
    }

    // ---- S = q @ k^T ----
    f32x4 sacc[4][4];
    #pragma unroll
    for (int mt=0;mt<4;++mt)
      #pragma unroll
      for (int nt=0;nt<4;++nt)
        sacc[mt][nt] = (f32x4){0.f,0.f,0.f,0.f};
    {
      bf16x8 aq[4], bk[4];
      #pragma unroll
      for (int mt=0;mt<4;++mt)
        aq[mt] = *(const bf16x8*)&slotA[(mt*16+rowa)*LDS_S + kg*8];
      #pragma unroll
      for (int nt=0;nt<4;++nt)
        bk[nt] = *(const bf16x8*)&slotB[(nt*16+rowa)*LDS_S + kg*8];
      __builtin_amdgcn_s_setprio(1);
      #pragma unroll
      for (int mt=0;mt<4;++mt)
        #pragma unroll
        for (int nt=0;nt<4;++nt)
          sacc[mt][nt] = __builtin_amdgcn_mfma_f32_16x16x32_bf16(aq[mt], bk[nt], sacc[mt][nt], 0, 0, 0);
      __builtin_amdgcn_s_setprio(0);
    }

    // ---- v -> vT [32][72] in slotB ----
    {
      f32x4 accv[4][2];
      #pragma unroll
      for (int mt=0;mt<4;++mt){ accv[mt][0]=(f32x4){0,0,0,0}; accv[mt][1]=(f32x4){0,0,0,0}; }
      #pragma unroll
      for (int kt=0;kt<8;++kt){
        bf16x8 av[4], bw[2];
        #pragma unroll
        for (int mt=0;mt<4;++mt)
          av[mt] = FRAG(shf, mt, 8, kt, ln);
        #pragma unroll
        for (int nt=0;nt<2;++nt)
          bw[nt] = WF(wqkv, 32 + tq + nt, 8, kt, ln);
        #pragma unroll
        for (int mt=0;mt<4;++mt)
          #pragma unroll
          for (int nt=0;nt<2;++nt)
            accv[mt][nt] = __builtin_amdgcn_mfma_f32_16x16x32_bf16(av[mt], bw[nt], accv[mt][nt], 0, 0, 0);
      }
      #pragma unroll
      for (int nt=0;nt<2;++nt){
        const float bias = inb[512 + hc + nt*16 + rowa];
        #pragma unroll
        for (int mt=0;mt<4;++mt)
          #pragma unroll
          for (int i=0;i<4;++i)
            slotB[(nt*16 + rowa)*LDVT + mt*16 + kg*4 + i] = f2bf(accv[mt][nt][i] + bias);
      }
    }

    // ---- softmax ----
    #pragma unroll
    for (int mt=0;mt<4;++mt){
      #pragma unroll
      for (int i=0;i<4;++i){
        float v0 = sacc[mt][0][i]*scale;
        float v1 = sacc[mt][1][i]*scale;
        float v2 = sacc[mt][2][i]*scale;
        float v3 = sacc[mt][3][i]*scale;
        float mx = fmaxf(fmaxf(v0,v1), fmaxf(v2,v3));
        #pragma unroll
        for (int d=1; d<16; d<<=1) mx = fmaxf(mx, __shfl_xor(mx, d, 64));
        v0 = __expf(v0-mx); v1 = __expf(v1-mx); v2 = __expf(v2-mx); v3 = __expf(v3-mx);
        float sm = v0+v1+v2+v3;
        #pragma unroll
        for (int d=1; d<16; d<<=1) sm += __shfl_xor(sm, d, 64);
        const float inv = 1.f / sm;
        sacc[mt][0][i] = v0*inv; sacc[mt][1][i] = v1*inv;
        sacc[mt][2][i] = v2*inv; sacc[mt][3][i] = v3*inv;
      }
    }

    // ---- PV in two kv-chunks of 32, P through slotA ----
    #pragma unroll
    for (int ck=0; ck<2; ++ck){
      #pragma unroll
      for (int ntl=0; ntl<2; ++ntl)
        #pragma unroll
        for (int mt=0;mt<4;++mt)
          #pragma unroll
          for (int i=0;i<4;++i)
            slotA[(mt*16 + kg*4 + i)*LDS_S + ntl*16 + rowa] = f2bf(sacc[mt][2*ck+ntl][i]);
      bf16x8 ap[4], bv[2];
      #pragma unroll
      for (int mt=0;mt<4;++mt)
        ap[mt] = *(const bf16x8*)&slotA[(mt*16+rowa)*LDS_S + kg*8];
      #pragma unroll
      for (int nt=0;nt<2;++nt)
        bv[nt] = *(const bf16x8*)&slotB[(nt*16+rowa)*LDVT + ck*32 + kg*8];
      __builtin_amdgcn_s_setprio(1);
      #pragma unroll
      for (int mt=0;mt<4;++mt)
        #pragma unroll
        for (int nt=0;nt<2;++nt)
          oacc[mt][hd*2+nt] = __builtin_amdgcn_mfma_f32_16x16x32_bf16(ap[mt], bv[nt], oacc[mt][hd*2+nt], 0, 0, 0);
      __builtin_amdgcn_s_setprio(0);
    }
  }

  __syncthreads();   // done with h (shf) & slots -> sh_o row-major o, xsh x-stash

  #pragma unroll
  for (int j=0;j<4;++j){
    const int col = wv*64 + j*16 + rowa;
    #pragma unroll
    for (int mt=0;mt<4;++mt)
      #pragma unroll
      for (int i=0;i<4;++i)
        sh_o[(mt*16 + kg*4 + i)*LDH + col] = f2bf(oacc[mt][j][i]);
  }
  {
    const int cbeg = wv*64;
    #pragma unroll
    for (int q=0;q<8;++q){
      bf16x8 pk;
      #pragma unroll
      for (int e=0;e<4;++e){
        const unsigned w = xpk[q*4+e];
        pk[2*e]   = (short)(w & 0xffffu);
        pk[2*e+1] = (short)(w >> 16);
      }
      *(bf16x8*)&xsh[ln*LDH + cbeg + q*8] = pk;
    }
  }
  __syncthreads();

  // ---- out-proj SWAPPED: D'[ch][tok] = wout x o^T; + bias + x residual(LDS) -> win2T ----
  {
    f32x4 acc[4][4];
    #pragma unroll
    for (int c0=0;c0<4;++c0)
      #pragma unroll
      for (int t0=0;t0<4;++t0)
        acc[c0][t0] = (f32x4){0.f,0.f,0.f,0.f};
    for (int kt=0; kt<8; ++kt){
      bf16x8 aw[4], bo[4];
      #pragma unroll
      for (int c0=0;c0<4;++c0)
        aw[c0] = WF(wout, wv*4 + c0, 8, kt, ln);
      #pragma unroll
      for (int t0=0;t0<4;++t0)
        bo[t0] = *(const bf16x8*)&sh_o[(t0*16+rowa)*LDH + kt*32 + kg*8];
      #pragma unroll
      for (int c0=0;c0<4;++c0)
        #pragma unroll
        for (int t0=0;t0<4;++t0)
          acc[c0][t0] = __builtin_amdgcn_mfma_f32_16x16x32_bf16(aw[c0], bo[t0], acc[c0][t0], 0, 0, 0);
    }
    #pragma unroll
    for (int c0=0;c0<4;++c0){
      #pragma unroll
      for (int i=0;i<4;++i){
        const int ch = wv*64 + c0*16 + kg*4 + i;
        const float bias = outb[ch];
        #pragma unroll
        for (int t0=0;t0<4;++t0){
          const int tok = t0*16 + rowa;
          const float res = bf2f(xsh[tok*LDH + ch]);
          win2T[(wi<<14) + ch*64 + tok] = f2bf(acc[c0][t0][i] + bias + res);
        }
      }
    }
  }
}

// ---------------- kernel 2: LN2 + pipelined MLP (frag-packed Yf/Mf) ----------------
// LDS (51200 B -> 3 blocks/CU): Yf frag h2 32768 | Mf frag m-chunk 16384 | red 2048
#define K2_OFF_M   32768
#define K2_OFF_RED 49152
#define K2_SMEM    51200

// GEMM1(chunk): acc1[rt][ct] += w1-rows x Y-tokens (swapped, D[hid][tok])
__device__ __forceinline__ void g1_step(const short* __restrict__ w1, const short* Yf,
                                        int chk, int kt, int wv, int ln,
                                        f32x4 acc1[2][4]){
  bf16x8 aw[2], bh[4];
  #pragma unroll
  for (int rt=0;rt<2;++rt)
    aw[rt] = WF(w1, chk*8 + wv*2 + rt, 8, kt, ln);
  #pragma unroll
  for (int ct=0;ct<4;++ct)
    bh[ct] = FRAG(Yf, ct, 8, kt, ln);
  #pragma unroll
  for (int rt=0;rt<2;++rt)
    #pragma unroll
    for (int ct=0;ct<4;++ct)
      acc1[rt][ct] = __builtin_amdgcn_mfma_f32_16x16x32_bf16(aw[rt], bh[ct], acc1[rt][ct], 0, 0, 0);
}

// GEMM2(chunk) SWAPPED: acc2[c0][t0] += w2-ch-rows x M-tokens (Mf frag-packed)
__device__ __forceinline__ void g2_step(const short* Mf, const short* __restrict__ w2,
                                        int chk, int kt2, int wv, int ln,
                                        f32x4 acc2[4][4]){
  bf16x8 aw2[4], bm[4];
  #pragma unroll
  for (int c0=0;c0<4;++c0)
    aw2[c0] = WF(w2, wv*4 + c0, 32, chk*4 + kt2, ln);
  #pragma unroll
  for (int t0=0;t0<4;++t0)
    bm[t0] = FRAG(Mf, t0, 4, kt2, ln);
  #pragma unroll
  for (int c0=0;c0<4;++c0)
    #pragma unroll
    for (int t0=0;t0<4;++t0)
      acc2[c0][t0] = __builtin_amdgcn_mfma_f32_16x16x32_bf16(aw2[c0], bm[t0], acc2[c0][t0], 0, 0, 0);
}

// GELU(acc1)+bias -> Mf frag-packed (b64 writes)
// element (tok=ct*16+rowa, hid=wv*32+rt*16+kg*4+i): kt2=wv, kgc=rt*2+(kg>>1), e=(kg&1)*4+i
__device__ __forceinline__ void mlp_gelu_store(short* Mf, const float* __restrict__ b1,
                                               int chk, int wv, int rowa, int kg,
                                               const f32x4 acc1[2][4]){
  #pragma unroll
  for (int rt=0;rt<2;++rt){
    const int hidb = wv*32 + rt*16 + kg*4;
    const f32x4 b1v = *(const f32x4*)&b1[chk*128 + hidb];
    #pragma unroll
    for (int ct=0;ct<4;++ct){
      bf16x4 st;
      #pragma unroll
      for (int i=0;i<4;++i)
        st[i] = f2bf(gelu_f(acc1[rt][ct][i] + b1v[i]));
      *(bf16x4*)&Mf[(((ct*4 + wv)*64) + (rt*2 + (kg>>1))*16 + rowa)*8 + (kg&1)*4] = st;
    }
  }
}

__global__ __launch_bounds__(256, 3)
void swin_mlp_kernel(const short* __restrict__ win2T,
                     const float* __restrict__ ln2w, const float* __restrict__ ln2b,
                     const float* __restrict__ b1,   const float* __restrict__ b2,
                     const short* __restrict__ w1,   const short* __restrict__ w2,
                     float* __restrict__ out)
{
  __shared__ char smem[K2_SMEM];
  short* Yf = (short*)smem;
  short* Mf = (short*)(smem + K2_OFF_M);
  float* red_s  = (float*)(smem + K2_OFF_RED);
  float* red_q2 = red_s + 256;

  const int tid = threadIdx.x;
  const int wv  = tid >> 6;
  const int ln  = tid & 63;
  const int rowa = ln & 15;
  const int kg   = ln >> 4;

  const int bid = blockIdx.x;
  const int wi  = ((bid & 7) << 8) | (bid >> 3);   // XCD swizzle
  const int wb = wi << 14;

  // ---- LN2 from win2T (coalesced rows) -> Yf frag-packed ----
  {
    float vals[64];
    float s = 0.f, sq = 0.f;
    const int cbeg = wv*64;
    #pragma unroll
    for (int j=0;j<64;++j){
      float v = bf2f(win2T[wb + (cbeg + j)*64 + ln]);
      vals[j] = v; s += v; sq += v*v;
    }
    red_s[cbeg + ln]  = s;
    red_q2[cbeg + ln] = sq;
    __syncthreads();
    float sum = red_s[ln] + red_s[64+ln] + red_s[128+ln] + red_s[192+ln];
    float ssq = red_q2[ln] + red_q2[64+ln] + red_q2[128+ln] + red_q2[192+ln];
    float mean = sum * 0.00390625f;
    float var  = ssq * 0.00390625f - mean*mean;
    float rstd = rsqrtf(var + 1e-5f);
    const int ttile = ln >> 4;
    #pragma unroll
    for (int kl=0;kl<2;++kl){
      const int kt = wv*2 + kl;
      #pragma unroll
      for (int kgw=0;kgw<4;++kgw){
        bf16x8 pkv;
        #pragma unroll
        for (int e=0;e<8;++e){
          const int j = kl*32 + kgw*8 + e;
          const int c = cbeg + j;
          pkv[e] = f2bf((vals[j] - mean) * rstd * ln2w[c] + ln2b[c]);
        }
        *(bf16x8*)&Yf[(((ttile*8 + kt)*64) + kgw*16 + (ln & 15))*8] = pkv;
      }
    }
  }
  __syncthreads();

  // ---- pipelined MLP, kt-interleaved: G1(c+1) woven with G2(c) (round-9 structure) ----
  f32x4 acc2[4][4];
  #pragma unroll
  for (int c0=0;c0<4;++c0)
    #pragma unroll
    for (int t0=0;t0<4;++t0)
      acc2[c0][t0] = (f32x4){0.f,0.f,0.f,0.f};

  // prologue: chunk 0 -> Mf
  {
    f32x4 acc1[2][4];
    #pragma unroll
    for (int rt=0;rt<2;++rt)
      #pragma unroll
      for (int ct=0;ct<4;++ct)
        acc1[rt][ct] = (f32x4){0.f,0.f,0.f,0.f};
    #pragma unroll
    for (int kt=0;kt<8;++kt) g1_step(w1, Yf, 0, kt, wv, ln, acc1);
    mlp_gelu_store(Mf, b1, 0, wv, rowa, kg, acc1);
  }
  __syncthreads();   // Mf(0) ready

  #pragma unroll
  for (int c = 0; c < 8; ++c){
    if (c < 7){
      f32x4 acc1n[2][4];
      #pragma unroll
      for (int rt=0;rt<2;++rt)
        #pragma unroll
        for (int ct=0;ct<4;++ct)
          acc1n[rt][ct] = (f32x4){0.f,0.f,0.f,0.f};
      #pragma unroll
      for (int kt=0;kt<4;++kt){
        g1_step(w1, Yf, c+1, kt, wv, ln, acc1n);
        g2_step(Mf, w2, c, kt, wv, ln, acc2);
      }
      #pragma unroll
      for (int kt=4;kt<8;++kt)
        g1_step(w1, Yf, c+1, kt, wv, ln, acc1n);
      __syncthreads();   // all Mf(c) reads done
      mlp_gelu_store(Mf, b1, c+1, wv, rowa, kg, acc1n);
      __syncthreads();   // Mf(c+1) ready
    } else {
      #pragma unroll
      for (int kt=0;kt<4;++kt)
        g2_step(Mf, w2, c, kt, wv, ln, acc2);
    }
  }

  // ---- epilogue: D'[ch][tok]: + b2 + win2T residual (coalesced), coalesced NCHW store ----
  const int b  = wi >> 8;
  const int wh = (wi >> 4) & 15;
  const int ww = wi & 15;
  #pragma unroll
  for (int c0=0;c0<4;++c0){
    #pragma unroll
    for (int i=0;i<4;++i){
      const int ch = wv*64 + c0*16 + kg*4 + i;
      const float bias = b2[ch];
      #pragma unroll
      for (int t0=0;t0<4;++t0){
        const int tok = t0*16 + rowa;
        float v = acc2[c0][t0][i] + bias + bf2f(win2T[wb + ch*64 + tok]);
        const int r = tok >> 3, cw = tok & 7;
        const int hh = (wh*8 + r + 4) & 127;
        const int wcc = (ww*8 + cw + 4) & 127;
        out[(((b<<8) + ch) << 14) + hh*128 + wcc] = v;
      }
    }
  }
}

// ---------------- launch ----------------
extern "C" void kernel_launch(void* const* d_in, const int* in_sizes, int n_in,
                              void* d_out, int out_size, void* d_ws, size_t ws_size,
                              hipStream_t stream) {
  (void)in_sizes; (void)n_in; (void)out_size; (void)ws_size;
  const float* x    = (const float*)d_in[0];
  const float* ln1w = (const float*)d_in[1];
  const float* ln1b = (const float*)d_in[2];
  const float* inw  = (const float*)d_in[3];
  const float* inb  = (const float*)d_in[4];
  const float* outw = (const float*)d_in[5];
  const float* outb = (const float*)d_in[6];
  const float* ln2w = (const float*)d_in[7];
  const float* ln2b = (const float*)d_in[8];
  const float* w1f  = (const float*)d_in[9];
  const float* b1   = (const float*)d_in[10];
  const float* w2f  = (const float*)d_in[11];
  const float* b2   = (const float*)d_in[12];
  float* out = (float*)d_out;

  short* ws    = (short*)d_ws;
  short* wqkv  = ws;            // 768*256   (frag-packed, KT=8)
  short* wout  = ws + 196608;   // 256*256   (frag-packed, KT=8)
  short* w1b   = ws + 262144;   // 1024*256  (frag-packed, KT=8)
  short* w2b   = ws + 524288;   // 256*1024  (frag-packed, KT=32)
  short* win2T = ws + 786432;   // 2048 x 256ch x 64tok bf16

  hipLaunchKernelGGL(wpack_kernel, dim3(96),  dim3(256), 0, stream, inw,  wqkv, 256);
  hipLaunchKernelGGL(wpack_kernel, dim3(32),  dim3(256), 0, stream, outw, wout, 256);
  hipLaunchKernelGGL(wpack_kernel, dim3(128), dim3(256), 0, stream, w1f,  w1b,  256);
  hipLaunchKernelGGL(wpack_kernel, dim3(128), dim3(256), 0, stream, w2f,  w2b,  1024);

  hipLaunchKernelGGL(swin_attn_kernel, dim3(2048), dim3(256), 0, stream,
                     x, ln1w, ln1b, inb, outb, wqkv, wout, win2T);
  hipLaunchKernelGGL(swin_mlp_kernel, dim3(2048), dim3(256), 0, stream,
                     win2T, ln2w, ln2b, b1, b2, w1b, w2b, out);
}

// Round 12
// 460.801 us; speedup vs baseline: 1.1743x; 1.1116x over previous
//
#include <hip/hip_runtime.h>
#include <math.h>

// Swin block: B=8, C=256, H=W=128, WS=8, SS=4, NH=8, dh=32
// Weights frag-packed: wf[((tile*KT+kt)*64+l)*8+e] = W[tile*16+(l&15)][kt*32+(l>>4)*8+e]
// attn: x read once (reg stash), XCD swizzle, frag-packed h.
// mlp: half-chunk (64-hidden) pipeline, double-buffered Mf, 1 barrier/chunk,
//      acc1=16 regs -> unified regs <=170 -> 3 blocks/CU.

#define LDH 264   // bf16 row stride for row-major [64][256] tiles (o, xsh)
#define LDS_S 40  // per-wave q/k slots [64][40]
#define LDVT 72   // vT [32][72]

typedef __attribute__((ext_vector_type(8))) short bf16x8;
typedef __attribute__((ext_vector_type(4))) short bf16x4;
typedef __attribute__((ext_vector_type(4))) float f32x4;

#define WF(wf, tile, KT, kt, ln) (*(const bf16x8*)&(wf)[((((tile)*(KT)) + (kt))*64 + (ln))*8])
// frag-packed LDS tile (4 token-tiles x KT k-steps): FRAG(base, ttile, KT, kt, lane)
#define FRAG(basep, ttile, KT, kt, l) (*(const bf16x8*)&(basep)[((((ttile)*(KT)) + (kt))*64 + (l))*8])

static __device__ __forceinline__ float bf2f(short s){
  union { unsigned u; float f; } cv;
  cv.u = ((unsigned)(unsigned short)s) << 16;
  return cv.f;
}
static __device__ __forceinline__ short f2bf(float f){
  union { float f; unsigned u; } cv; cv.f = f;
  unsigned r = (cv.u + 0x7FFFu + ((cv.u >> 16) & 1u)) >> 16;  // RNE
  return (short)r;
}
static __device__ __forceinline__ float gelu_f(float x){
  return 0.5f * x * (1.0f + erff(x * 0.7071067811865475f));
}

// ---------------- K0: fp32 -> bf16 fragment-order repack ----------------
__global__ void wpack_kernel(const float* __restrict__ src, short* __restrict__ dst,
                             int K){
  const int t8 = blockIdx.x * 256 + threadIdx.x;
  const int e0 = t8 * 8;
  const int l   = (e0 >> 3) & 63;
  const int blk = e0 >> 9;
  const int KT  = K >> 5;
  const int kt   = blk % KT;
  const int tile = blk / KT;
  const int row = tile*16 + (l & 15);
  const int kb  = kt*32 + (l >> 4)*8;
  const float* s = src + row*K + kb;
  bf16x8 o;
  #pragma unroll
  for (int e=0;e<8;++e) o[e] = f2bf(s[e]);
  *(bf16x8*)&dst[e0] = o;
}

// ---------------- kernel 1: LN1 + QKV + attention + out-proj(swapped) -> win2T ----------------
#define K1_OFF_WV  33792
#define K1_OFF_RED 74752
#define K1_SMEM    76800

__global__ __launch_bounds__(256, 2)
void swin_attn_kernel(const float* __restrict__ x,
                      const float* __restrict__ ln1w, const float* __restrict__ ln1b,
                      const float* __restrict__ inb,  const float* __restrict__ outb,
                      const short* __restrict__ wqkv, const short* __restrict__ wout,
                      short* __restrict__ win2T)
{
  __shared__ char smem[K1_SMEM];
  short* shf    = (short*)smem;                 // h frag-packed (32768 B), then o row-major [64][264]
  short* sh_o   = (short*)smem;
  short* xsh    = (short*)(smem + K1_OFF_WV);   // x bf16 stash row-major (post-attention)
  float* red_s  = (float*)(smem + K1_OFF_RED);
  float* red_q2 = red_s + 256;

  const int tid = threadIdx.x;
  const int wv  = tid >> 6;
  const int ln  = tid & 63;
  const int rowa = ln & 15;
  const int kg   = ln >> 4;

  short* slotA = (short*)(smem + K1_OFF_WV) + wv*5120;
  short* slotB = slotA + 2560;

  const int bid = blockIdx.x;
  const int wi  = ((bid & 7) << 8) | (bid >> 3);   // XCD swizzle (2048%8==0, bijective)
  const int b  = wi >> 8;
  const int wh = (wi >> 4) & 15;
  const int ww = wi & 15;

  const int hh = (wh*8 + (ln >> 3) + 4) & 127;
  const int wc = (ww*8 + (ln & 7) + 4) & 127;
  const int offhw = hh*128 + wc;
  const int xbase = b << 22;

  unsigned xpk[32];
  {
    const int cbeg = wv*64;
    float vals[64];
    float s = 0.f, sq = 0.f;
    #pragma unroll
    for (int j = 0; j < 64; ++j){
      float v = x[xbase + ((cbeg + j) << 14) + offhw];
      vals[j] = v; s += v; sq += v*v;
    }
    #pragma unroll
    for (int p = 0; p < 32; ++p){
      const unsigned lo = (unsigned)(unsigned short)f2bf(vals[2*p]);
      const unsigned hi = (unsigned)(unsigned short)f2bf(vals[2*p+1]);
      xpk[p] = lo | (hi << 16);
    }
    red_s[cbeg + ln]  = s;
    red_q2[cbeg + ln] = sq;
    __syncthreads();
    float sum = red_s[ln] + red_s[64+ln] + red_s[128+ln] + red_s[192+ln];
    float ssq = red_q2[ln] + red_q2[64+ln] + red_q2[128+ln] + red_q2[192+ln];
    float mean = sum * 0.00390625f;
    float var  = ssq * 0.00390625f - mean*mean;
    float rstd = rsqrtf(var + 1e-5f);
    // h frag-packed write
    const int ttile = ln >> 4;
    #pragma unroll
    for (int kl=0;kl<2;++kl){
      const int kt = wv*2 + kl;
      #pragma unroll
      for (int kgw=0;kgw<4;++kgw){
        bf16x8 pkv;
        #pragma unroll
        for (int e=0;e<8;++e){
          const int j = kl*32 + kgw*8 + e;
          const int c = cbeg + j;
          pkv[e] = f2bf((vals[j] - mean) * rstd * ln1w[c] + ln1b[c]);
        }
        *(bf16x8*)&shf[(((ttile*8 + kt)*64) + kgw*16 + (ln & 15))*8] = pkv;
      }
    }
  }
  __syncthreads();

  const float scale = 0.1767766952966369f;
  f32x4 oacc[4][4];
  #pragma unroll
  for (int mt=0;mt<4;++mt)
    #pragma unroll
    for (int j=0;j<4;++j)
      oacc[mt][j] = (f32x4){0.f,0.f,0.f,0.f};

  #pragma unroll
  for (int hd = 0; hd < 2; ++hd){
    const int hc = (2*wv + hd) * 32;
    const int tq = (2*wv + hd) * 2;

    // ---- q + k fused (shared A-frags from frag-packed h) ----
    {
      f32x4 aq[4][2], ak[4][2];
      #pragma unroll
      for (int mt=0;mt<4;++mt){
        aq[mt][0]=(f32x4){0,0,0,0}; aq[mt][1]=(f32x4){0,0,0,0};
        ak[mt][0]=(f32x4){0,0,0,0}; ak[mt][1]=(f32x4){0,0,0,0};
      }
      #pragma unroll
      for (int kt=0;kt<8;++kt){
        bf16x8 av[4], bq[2], bk[2];
        #pragma unroll
        for (int mt=0;mt<4;++mt)
          av[mt] = FRAG(shf, mt, 8, kt, ln);
        #pragma unroll
        for (int nt=0;nt<2;++nt){
          bq[nt] = WF(wqkv, tq + nt,      8, kt, ln);
          bk[nt] = WF(wqkv, 16 + tq + nt, 8, kt, ln);
        }
        #pragma unroll
        for (int mt=0;mt<4;++mt)
          #pragma unroll
          for (int nt=0;nt<2;++nt){
            aq[mt][nt] = __builtin_amdgcn_mfma_f32_16x16x32_bf16(av[mt], bq[nt], aq[mt][nt], 0, 0, 0);
            ak[mt][nt] = __builtin_amdgcn_mfma_f32_16x16x32_bf16(av[mt], bk[nt], ak[mt][nt], 0, 0, 0);
          }
      }
      #pragma unroll
      for (int nt=0;nt<2;++nt){
        const float biasq = inb[hc + nt*16 + rowa];
        const float biask = inb[256 + hc + nt*16 + rowa];
        #pragma unroll
        for (int mt=0;mt<4;++mt)
          #pragma unroll
          for (int i=0;i<4;++i){
            slotA[(mt*16 + kg*4 + i)*LDS_S + nt*16 + rowa] = f2bf(aq[mt][nt][i] + biasq);
            slotB[(mt*16 + kg*4 + i)*LDS_S + nt*16 + rowa] = f2bf(ak[mt][nt][i] + biask);
          }
      }
    }

    // ---- S = q @ k^T ----
    f32x4 sacc[4][4];
    #pragma unroll
    for (int mt=0;mt<4;++mt)
      #pragma unroll
      for (int nt=0;nt<4;++nt)
        sacc[mt][nt] = (f32x4){0.f,0.f,0.f,0.f};
    {
      bf16x8 aq[4], bk[4];
      #pragma unroll
      for (int mt=0;mt<4;++mt)
        aq[mt] = *(const bf16x8*)&slotA[(mt*16+rowa)*LDS_S + kg*8];
      #pragma unroll
      for (int nt=0;nt<4;++nt)
        bk[nt] = *(const bf16x8*)&slotB[(nt*16+rowa)*LDS_S + kg*8];
      __builtin_amdgcn_s_setprio(1);
      #pragma unroll
      for (int mt=0;mt<4;++mt)
        #pragma unroll
        for (int nt=0;nt<4;++nt)
          sacc[mt][nt] = __builtin_amdgcn_mfma_f32_16x16x32_bf16(aq[mt], bk[nt], sacc[mt][nt], 0, 0, 0);
      __builtin_amdgcn_s_setprio(0);
    }

    // ---- v -> vT [32][72] in slotB ----
    {
      f32x4 accv[4][2];
      #pragma unroll
      for (int mt=0;mt<4;++mt){ accv[mt][0]=(f32x4){0,0,0,0}; accv[mt][1]=(f32x4){0,0,0,0}; }
      #pragma unroll
      for (int kt=0;kt<8;++kt){
        bf16x8 av[4], bw[2];
        #pragma unroll
        for (int mt=0;mt<4;++mt)
          av[mt] = FRAG(shf, mt, 8, kt, ln);
        #pragma unroll
        for (int nt=0;nt<2;++nt)
          bw[nt] = WF(wqkv, 32 + tq + nt, 8, kt, ln);
        #pragma unroll
        for (int mt=0;mt<4;++mt)
          #pragma unroll
          for (int nt=0;nt<2;++nt)
            accv[mt][nt] = __builtin_amdgcn_mfma_f32_16x16x32_bf16(av[mt], bw[nt], accv[mt][nt], 0, 0, 0);
      }
      #pragma unroll
      for (int nt=0;nt<2;++nt){
        const float bias = inb[512 + hc + nt*16 + rowa];
        #pragma unroll
        for (int mt=0;mt<4;++mt)
          #pragma unroll
          for (int i=0;i<4;++i)
            slotB[(nt*16 + rowa)*LDVT + mt*16 + kg*4 + i] = f2bf(accv[mt][nt][i] + bias);
      }
    }

    // ---- softmax ----
    #pragma unroll
    for (int mt=0;mt<4;++mt){
      #pragma unroll
      for (int i=0;i<4;++i){
        float v0 = sacc[mt][0][i]*scale;
        float v1 = sacc[mt][1][i]*scale;
        float v2 = sacc[mt][2][i]*scale;
        float v3 = sacc[mt][3][i]*scale;
        float mx = fmaxf(fmaxf(v0,v1), fmaxf(v2,v3));
        #pragma unroll
        for (int d=1; d<16; d<<=1) mx = fmaxf(mx, __shfl_xor(mx, d, 64));
        v0 = __expf(v0-mx); v1 = __expf(v1-mx); v2 = __expf(v2-mx); v3 = __expf(v3-mx);
        float sm = v0+v1+v2+v3;
        #pragma unroll
        for (int d=1; d<16; d<<=1) sm += __shfl_xor(sm, d, 64);
        const float inv = 1.f / sm;
        sacc[mt][0][i] = v0*inv; sacc[mt][1][i] = v1*inv;
        sacc[mt][2][i] = v2*inv; sacc[mt][3][i] = v3*inv;
      }
    }

    // ---- PV in two kv-chunks of 32, P through slotA ----
    #pragma unroll
    for (int ck=0; ck<2; ++ck){
      #pragma unroll
      for (int ntl=0; ntl<2; ++ntl)
        #pragma unroll
        for (int mt=0;mt<4;++mt)
          #pragma unroll
          for (int i=0;i<4;++i)
            slotA[(mt*16 + kg*4 + i)*LDS_S + ntl*16 + rowa] = f2bf(sacc[mt][2*ck+ntl][i]);
      bf16x8 ap[4], bv[2];
      #pragma unroll
      for (int mt=0;mt<4;++mt)
        ap[mt] = *(const bf16x8*)&slotA[(mt*16+rowa)*LDS_S + kg*8];
      #pragma unroll
      for (int nt=0;nt<2;++nt)
        bv[nt] = *(const bf16x8*)&slotB[(nt*16+rowa)*LDVT + ck*32 + kg*8];
      __builtin_amdgcn_s_setprio(1);
      #pragma unroll
      for (int mt=0;mt<4;++mt)
        #pragma unroll
        for (int nt=0;nt<2;++nt)
          oacc[mt][hd*2+nt] = __builtin_amdgcn_mfma_f32_16x16x32_bf16(ap[mt], bv[nt], oacc[mt][hd*2+nt], 0, 0, 0);
      __builtin_amdgcn_s_setprio(0);
    }
  }

  __syncthreads();   // done with h (shf) & slots -> sh_o row-major o, xsh x-stash

  #pragma unroll
  for (int j=0;j<4;++j){
    const int col = wv*64 + j*16 + rowa;
    #pragma unroll
    for (int mt=0;mt<4;++mt)
      #pragma unroll
      for (int i=0;i<4;++i)
        sh_o[(mt*16 + kg*4 + i)*LDH + col] = f2bf(oacc[mt][j][i]);
  }
  {
    const int cbeg = wv*64;
    #pragma unroll
    for (int q=0;q<8;++q){
      bf16x8 pk;
      #pragma unroll
      for (int e=0;e<4;++e){
        const unsigned w = xpk[q*4+e];
        pk[2*e]   = (short)(w & 0xffffu);
        pk[2*e+1] = (short)(w >> 16);
      }
      *(bf16x8*)&xsh[ln*LDH + cbeg + q*8] = pk;
    }
  }
  __syncthreads();

  // ---- out-proj SWAPPED: D'[ch][tok] = wout x o^T; + bias + x residual(LDS) -> win2T ----
  {
    f32x4 acc[4][4];
    #pragma unroll
    for (int c0=0;c0<4;++c0)
      #pragma unroll
      for (int t0=0;t0<4;++t0)
        acc[c0][t0] = (f32x4){0.f,0.f,0.f,0.f};
    for (int kt=0; kt<8; ++kt){
      bf16x8 aw[4], bo[4];
      #pragma unroll
      for (int c0=0;c0<4;++c0)
        aw[c0] = WF(wout, wv*4 + c0, 8, kt, ln);
      #pragma unroll
      for (int t0=0;t0<4;++t0)
        bo[t0] = *(const bf16x8*)&sh_o[(t0*16+rowa)*LDH + kt*32 + kg*8];
      #pragma unroll
      for (int c0=0;c0<4;++c0)
        #pragma unroll
        for (int t0=0;t0<4;++t0)
          acc[c0][t0] = __builtin_amdgcn_mfma_f32_16x16x32_bf16(aw[c0], bo[t0], acc[c0][t0], 0, 0, 0);
    }
    #pragma unroll
    for (int c0=0;c0<4;++c0){
      #pragma unroll
      for (int i=0;i<4;++i){
        const int ch = wv*64 + c0*16 + kg*4 + i;
        const float bias = outb[ch];
        #pragma unroll
        for (int t0=0;t0<4;++t0){
          const int tok = t0*16 + rowa;
          const float res = bf2f(xsh[tok*LDH + ch]);
          win2T[(wi<<14) + ch*64 + tok] = f2bf(acc[c0][t0][i] + bias + res);
        }
      }
    }
  }
}

// ---------------- kernel 2: LN2 + half-chunk pipelined MLP (dbuf Mf) ----------------
// LDS (51200 B -> 3 blocks/CU): Yf 32768 | Mf 2 x 8192 | red 2048
#define K2_OFF_M   32768
#define K2_OFF_RED 49152
#define K2_SMEM    51200

// G1 half-chunk step: acc1[ct] += w1-tile(c*4+wv) x Y-token-tile(ct) at k-step kt
__device__ __forceinline__ void g1h(const short* __restrict__ w1, const short* Yf,
                                    int c, int kt, int wv, int ln, f32x4 acc1[4]){
  const bf16x8 aw = WF(w1, c*4 + wv, 8, kt, ln);
  bf16x8 bh[4];
  #pragma unroll
  for (int ct=0;ct<4;++ct)
    bh[ct] = FRAG(Yf, ct, 8, kt, ln);
  #pragma unroll
  for (int ct=0;ct<4;++ct)
    acc1[ct] = __builtin_amdgcn_mfma_f32_16x16x32_bf16(aw, bh[ct], acc1[ct], 0, 0, 0);
}

// G2 half-chunk step: acc2[c0][t0] += w2(ch rows, hidden c*64+kt2*32..) x M frag
__device__ __forceinline__ void g2h(const short* Mfb, const short* __restrict__ w2,
                                    int c, int kt2, int wv, int ln, f32x4 acc2[4][4]){
  bf16x8 aw2[4], bm[4];
  #pragma unroll
  for (int c0=0;c0<4;++c0)
    aw2[c0] = WF(w2, wv*4 + c0, 32, c*2 + kt2, ln);
  #pragma unroll
  for (int t0=0;t0<4;++t0)
    bm[t0] = FRAG(Mfb, t0, 2, kt2, ln);
  #pragma unroll
  for (int c0=0;c0<4;++c0)
    #pragma unroll
    for (int t0=0;t0<4;++t0)
      acc2[c0][t0] = __builtin_amdgcn_mfma_f32_16x16x32_bf16(aw2[c0], bm[t0], acc2[c0][t0], 0, 0, 0);
}

// GELU(acc1)+bias -> Mf frag-packed b64 writes
// element (tok=ct*16+rowa, hid_in_chunk=wv*16+kg*4+i):
//   kt2=wv>>1, lane-group=(wv&1)*2+(kg>>1), e=(kg&1)*4+i
__device__ __forceinline__ void gstore_h(short* Mfb, const float* __restrict__ b1,
                                         int c, int wv, int rowa, int kg,
                                         const f32x4 acc1[4]){
  const int hidb = c*64 + wv*16 + kg*4;
  const f32x4 b1v = *(const f32x4*)&b1[hidb];
  #pragma unroll
  for (int ct=0;ct<4;++ct){
    bf16x4 st;
    #pragma unroll
    for (int i=0;i<4;++i)
      st[i] = f2bf(gelu_f(acc1[ct][i] + b1v[i]));
    *(bf16x4*)&Mfb[(((ct*2 + (wv>>1))*64) + ((wv&1)*2 + (kg>>1))*16 + rowa)*8 + (kg&1)*4] = st;
  }
}

__global__ __launch_bounds__(256, 3)
void swin_mlp_kernel(const short* __restrict__ win2T,
                     const float* __restrict__ ln2w, const float* __restrict__ ln2b,
                     const float* __restrict__ b1,   const float* __restrict__ b2,
                     const short* __restrict__ w1,   const short* __restrict__ w2,
                     float* __restrict__ out)
{
  __shared__ char smem[K2_SMEM];
  short* Yf  = (short*)smem;
  short* Mf0 = (short*)(smem + K2_OFF_M);
  short* Mf1 = Mf0 + 4096;
  float* red_s  = (float*)(smem + K2_OFF_RED);
  float* red_q2 = red_s + 256;

  const int tid = threadIdx.x;
  const int wv  = tid >> 6;
  const int ln  = tid & 63;
  const int rowa = ln & 15;
  const int kg   = ln >> 4;

  const int bid = blockIdx.x;
  const int wi  = ((bid & 7) << 8) | (bid >> 3);   // XCD swizzle
  const int wb = wi << 14;

  // ---- LN2 from win2T (coalesced rows) -> Yf frag-packed ----
  {
    float vals[64];
    float s = 0.f, sq = 0.f;
    const int cbeg = wv*64;
    #pragma unroll
    for (int j=0;j<64;++j){
      float v = bf2f(win2T[wb + (cbeg + j)*64 + ln]);
      vals[j] = v; s += v; sq += v*v;
    }
    red_s[cbeg + ln]  = s;
    red_q2[cbeg + ln] = sq;
    __syncthreads();
    float sum = red_s[ln] + red_s[64+ln] + red_s[128+ln] + red_s[192+ln];
    float ssq = red_q2[ln] + red_q2[64+ln] + red_q2[128+ln] + red_q2[192+ln];
    float mean = sum * 0.00390625f;
    float var  = ssq * 0.00390625f - mean*mean;
    float rstd = rsqrtf(var + 1e-5f);
    const int ttile = ln >> 4;
    #pragma unroll
    for (int kl=0;kl<2;++kl){
      const int kt = wv*2 + kl;
      #pragma unroll
      for (int kgw=0;kgw<4;++kgw){
        bf16x8 pkv;
        #pragma unroll
        for (int e=0;e<8;++e){
          const int j = kl*32 + kgw*8 + e;
          const int c = cbeg + j;
          pkv[e] = f2bf((vals[j] - mean) * rstd * ln2w[c] + ln2b[c]);
        }
        *(bf16x8*)&Yf[(((ttile*8 + kt)*64) + kgw*16 + (ln & 15))*8] = pkv;
      }
    }
  }
  __syncthreads();

  // ---- half-chunk pipeline: 16 chunks of 64 hidden, dbuf Mf, 1 barrier/chunk ----
  f32x4 acc2[4][4];
  #pragma unroll
  for (int c0=0;c0<4;++c0)
    #pragma unroll
    for (int t0=0;t0<4;++t0)
      acc2[c0][t0] = (f32x4){0.f,0.f,0.f,0.f};

  f32x4 acc1[4];
  #pragma unroll
  for (int ct=0;ct<4;++ct) acc1[ct] = (f32x4){0.f,0.f,0.f,0.f};
  #pragma unroll
  for (int kt=0;kt<8;++kt) g1h(w1, Yf, 0, kt, wv, ln, acc1);   // prologue: G1(0)

  #pragma unroll
  for (int c = 0; c < 16; ++c){
    short* cur = (c & 1) ? Mf1 : Mf0;
    gstore_h(cur, b1, c, wv, rowa, kg, acc1);
    __syncthreads();   // cur(c) published; prior reads of cur's buffer fenced last iter
    if (c < 15){
      f32x4 acc1n[4];
      #pragma unroll
      for (int ct=0;ct<4;++ct) acc1n[ct] = (f32x4){0.f,0.f,0.f,0.f};
      #pragma unroll
      for (int kt=0;kt<4;++kt) g1h(w1, Yf, c+1, kt, wv, ln, acc1n);
      g2h(cur, w2, c, 0, wv, ln, acc2);
      #pragma unroll
      for (int kt=4;kt<8;++kt) g1h(w1, Yf, c+1, kt, wv, ln, acc1n);
      g2h(cur, w2, c, 1, wv, ln, acc2);
      #pragma unroll
      for (int ct=0;ct<4;++ct) acc1[ct] = acc1n[ct];
    } else {
      g2h(cur, w2, c, 0, wv, ln, acc2);
      g2h(cur, w2, c, 1, wv, ln, acc2);
    }
  }

  // ---- epilogue: D'[ch][tok]: + b2 + win2T residual (coalesced), coalesced NCHW store ----
  const int b  = wi >> 8;
  const int wh = (wi >> 4) & 15;
  const int ww = wi & 15;
  #pragma unroll
  for (int c0=0;c0<4;++c0){
    #pragma unroll
    for (int i=0;i<4;++i){
      const int ch = wv*64 + c0*16 + kg*4 + i;
      const float bias = b2[ch];
      #pragma unroll
      for (int t0=0;t0<4;++t0){
        const int tok = t0*16 + rowa;
        float v = acc2[c0][t0][i] + bias + bf2f(win2T[wb + ch*64 + tok]);
        const int r = tok >> 3, cw = tok & 7;
        const int hh = (wh*8 + r + 4) & 127;
        const int wcc = (ww*8 + cw + 4) & 127;
        out[(((b<<8) + ch) << 14) + hh*128 + wcc] = v;
      }
    }
  }
}

// ---------------- launch ----------------
extern "C" void kernel_launch(void* const* d_in, const int* in_sizes, int n_in,
                              void* d_out, int out_size, void* d_ws, size_t ws_size,
                              hipStream_t stream) {
  (void)in_sizes; (void)n_in; (void)out_size; (void)ws_size;
  const float* x    = (const float*)d_in[0];
  const float* ln1w = (const float*)d_in[1];
  const float* ln1b = (const float*)d_in[2];
  const float* inw  = (const float*)d_in[3];
  const float* inb  = (const float*)d_in[4];
  const float* outw = (const float*)d_in[5];
  const float* outb = (const float*)d_in[6];
  const float* ln2w = (const float*)d_in[7];
  const float* ln2b = (const float*)d_in[8];
  const float* w1f  = (const float*)d_in[9];
  const float* b1   = (const float*)d_in[10];
  const float* w2f  = (const float*)d_in[11];
  const float* b2   = (const float*)d_in[12];
  float* out = (float*)d_out;

  short* ws    = (short*)d_ws;
  short* wqkv  = ws;            // 768*256   (frag-packed, KT=8)
  short* wout  = ws + 196608;   // 256*256   (frag-packed, KT=8)
  short* w1b   = ws + 262144;   // 1024*256  (frag-packed, KT=8)
  short* w2b   = ws + 524288;   // 256*1024  (frag-packed, KT=32)
  short* win2T = ws + 786432;   // 2048 x 256ch x 64tok bf16

  hipLaunchKernelGGL(wpack_kernel, dim3(96),  dim3(256), 0, stream, inw,  wqkv, 256);
  hipLaunchKernelGGL(wpack_kernel, dim3(32),  dim3(256), 0, stream, outw, wout, 256);
  hipLaunchKernelGGL(wpack_kernel, dim3(128), dim3(256), 0, stream, w1f,  w1b,  256);
  hipLaunchKernelGGL(wpack_kernel, dim3(128), dim3(256), 0, stream, w2f,  w2b,  1024);

  hipLaunchKernelGGL(swin_attn_kernel, dim3(2048), dim3(256), 0, stream,
                     x, ln1w, ln1b, inb, outb, wqkv, wout, win2T);
  hipLaunchKernelGGL(swin_mlp_kernel, dim3(2048), dim3(256), 0, stream,
                     win2T, ln2w, ln2b, b1, b2, w1b, w2b, out);
}

// Round 13
// 431.606 us; speedup vs baseline: 1.2537x; 1.0676x over previous
//
#include <hip/hip_runtime.h>
#include <math.h>

// Swin block: B=8, C=256, H=W=128, WS=8, SS=4, NH=8, dh=32
// Weights frag-packed: wf[((tile*KT+kt)*64+l)*8+e] = W[tile*16+(l&15)][kt*32+(l>>4)*8+e]
// attn: x read once (reg stash), XCD swizzle, frag-packed h.
// mlp: half-chunk pipeline, dbuf Mf, REGISTER-PREFETCHED weight frags (2 waves/SIMD,
//      loads issued pre-barrier -> land under the MFMA phase).

#define LDH 264   // bf16 row stride for row-major [64][256] tiles (o, xsh)
#define LDS_S 40  // per-wave q/k slots [64][40]
#define LDVT 72   // vT [32][72]

typedef __attribute__((ext_vector_type(8))) short bf16x8;
typedef __attribute__((ext_vector_type(4))) short bf16x4;
typedef __attribute__((ext_vector_type(4))) float f32x4;

#define WF(wf, tile, KT, kt, ln) (*(const bf16x8*)&(wf)[((((tile)*(KT)) + (kt))*64 + (ln))*8])
// frag-packed LDS tile (4 token-tiles x KT k-steps): FRAG(base, ttile, KT, kt, lane)
#define FRAG(basep, ttile, KT, kt, l) (*(const bf16x8*)&(basep)[((((ttile)*(KT)) + (kt))*64 + (l))*8])

static __device__ __forceinline__ float bf2f(short s){
  union { unsigned u; float f; } cv;
  cv.u = ((unsigned)(unsigned short)s) << 16;
  return cv.f;
}
static __device__ __forceinline__ short f2bf(float f){
  union { float f; unsigned u; } cv; cv.f = f;
  unsigned r = (cv.u + 0x7FFFu + ((cv.u >> 16) & 1u)) >> 16;  // RNE
  return (short)r;
}
static __device__ __forceinline__ float gelu_f(float x){
  return 0.5f * x * (1.0f + erff(x * 0.7071067811865475f));
}

// ---------------- K0: fp32 -> bf16 fragment-order repack ----------------
__global__ void wpack_kernel(const float* __restrict__ src, short* __restrict__ dst,
                             int K){
  const int t8 = blockIdx.x * 256 + threadIdx.x;
  const int e0 = t8 * 8;
  const int l   = (e0 >> 3) & 63;
  const int blk = e0 >> 9;
  const int KT  = K >> 5;
  const int kt   = blk % KT;
  const int tile = blk / KT;
  const int row = tile*16 + (l & 15);
  const int kb  = kt*32 + (l >> 4)*8;
  const float* s = src + row*K + kb;
  bf16x8 o;
  #pragma unroll
  for (int e=0;e<8;++e) o[e] = f2bf(s[e]);
  *(bf16x8*)&dst[e0] = o;
}

// ---------------- kernel 1: LN1 + QKV + attention + out-proj(swapped) -> win2T ----------------
#define K1_OFF_WV  33792
#define K1_OFF_RED 74752
#define K1_SMEM    76800

__global__ __launch_bounds__(256, 2)
void swin_attn_kernel(const float* __restrict__ x,
                      const float* __restrict__ ln1w, const float* __restrict__ ln1b,
                      const float* __restrict__ inb,  const float* __restrict__ outb,
                      const short* __restrict__ wqkv, const short* __restrict__ wout,
                      short* __restrict__ win2T)
{
  __shared__ char smem[K1_SMEM];
  short* shf    = (short*)smem;                 // h frag-packed (32768 B), then o row-major [64][264]
  short* sh_o   = (short*)smem;
  short* xsh    = (short*)(smem + K1_OFF_WV);   // x bf16 stash row-major (post-attention)
  float* red_s  = (float*)(smem + K1_OFF_RED);
  float* red_q2 = red_s + 256;

  const int tid = threadIdx.x;
  const int wv  = tid >> 6;
  const int ln  = tid & 63;
  const int rowa = ln & 15;
  const int kg   = ln >> 4;

  short* slotA = (short*)(smem + K1_OFF_WV) + wv*5120;
  short* slotB = slotA + 2560;

  const int bid = blockIdx.x;
  const int wi  = ((bid & 7) << 8) | (bid >> 3);   // XCD swizzle (2048%8==0, bijective)
  const int b  = wi >> 8;
  const int wh = (wi >> 4) & 15;
  const int ww = wi & 15;

  const int hh = (wh*8 + (ln >> 3) + 4) & 127;
  const int wc = (ww*8 + (ln & 7) + 4) & 127;
  const int offhw = hh*128 + wc;
  const int xbase = b << 22;

  unsigned xpk[32];
  {
    const int cbeg = wv*64;
    float vals[64];
    float s = 0.f, sq = 0.f;
    #pragma unroll
    for (int j = 0; j < 64; ++j){
      float v = x[xbase + ((cbeg + j) << 14) + offhw];
      vals[j] = v; s += v; sq += v*v;
    }
    #pragma unroll
    for (int p = 0; p < 32; ++p){
      const unsigned lo = (unsigned)(unsigned short)f2bf(vals[2*p]);
      const unsigned hi = (unsigned)(unsigned short)f2bf(vals[2*p+1]);
      xpk[p] = lo | (hi << 16);
    }
    red_s[cbeg + ln]  = s;
    red_q2[cbeg + ln] = sq;
    __syncthreads();
    float sum = red_s[ln] + red_s[64+ln] + red_s[128+ln] + red_s[192+ln];
    float ssq = red_q2[ln] + red_q2[64+ln] + red_q2[128+ln] + red_q2[192+ln];
    float mean = sum * 0.00390625f;
    float var  = ssq * 0.00390625f - mean*mean;
    float rstd = rsqrtf(var + 1e-5f);
    // h frag-packed write
    const int ttile = ln >> 4;
    #pragma unroll
    for (int kl=0;kl<2;++kl){
      const int kt = wv*2 + kl;
      #pragma unroll
      for (int kgw=0;kgw<4;++kgw){
        bf16x8 pkv;
        #pragma unroll
        for (int e=0;e<8;++e){
          const int j = kl*32 + kgw*8 + e;
          const int c = cbeg + j;
          pkv[e] = f2bf((vals[j] - mean) * rstd * ln1w[c] + ln1b[c]);
        }
        *(bf16x8*)&shf[(((ttile*8 + kt)*64) + kgw*16 + (ln & 15))*8] = pkv;
      }
    }
  }
  __syncthreads();

  const float scale = 0.1767766952966369f;
  f32x4 oacc[4][4];
  #pragma unroll
  for (int mt=0;mt<4;++mt)
    #pragma unroll
    for (int j=0;j<4;++j)
      oacc[mt][j] = (f32x4){0.f,0.f,0.f,0.f};

  #pragma unroll
  for (int hd = 0; hd < 2; ++hd){
    const int hc = (2*wv + hd) * 32;
    const int tq = (2*wv + hd) * 2;

    // ---- q + k fused (shared A-frags from frag-packed h) ----
    {
      f32x4 aq[4][2], ak[4][2];
      #pragma unroll
      for (int mt=0;mt<4;++mt){
        aq[mt][0]=(f32x4){0,0,0,0}; aq[mt][1]=(f32x4){0,0,0,0};
        ak[mt][0]=(f32x4){0,0,0,0}; ak[mt][1]=(f32x4){0,0,0,0};
      }
      #pragma unroll
      for (int kt=0;kt<8;++kt){
        bf16x8 av[4], bq[2], bk[2];
        #pragma unroll
        for (int mt=0;mt<4;++mt)
          av[mt] = FRAG(shf, mt, 8, kt, ln);
        #pragma unroll
        for (int nt=0;nt<2;++nt){
          bq[nt] = WF(wqkv, tq + nt,      8, kt, ln);
          bk[nt] = WF(wqkv, 16 + tq + nt, 8, kt, ln);
        }
        #pragma unroll
        for (int mt=0;mt<4;++mt)
          #pragma unroll
          for (int nt=0;nt<2;++nt){
            aq[mt][nt] = __builtin_amdgcn_mfma_f32_16x16x32_bf16(av[mt], bq[nt], aq[mt][nt], 0, 0, 0);
            ak[mt][nt] = __builtin_amdgcn_mfma_f32_16x16x32_bf16(av[mt], bk[nt], ak[mt][nt], 0, 0, 0);
          }
      }
      #pragma unroll
      for (int nt=0;nt<2;++nt){
        const float biasq = inb[hc + nt*16 + rowa];
        const float biask = inb[256 + hc + nt*16 + rowa];
        #pragma unroll
        for (int mt=0;mt<4;++mt)
          #pragma unroll
          for (int i=0;i<4;++i){
            slotA[(mt*16 + kg*4 + i)*LDS_S + nt*16 + rowa] = f2bf(aq[mt][nt][i] + biasq);
            slotB[(mt*16 + kg*4 + i)*LDS_S + nt*16 + rowa] = f2bf(ak[mt][nt][i] + biask);
          }
      }
    }

    // ---- S = q @ k^T ----
    f32x4 sacc[4][4];
    #pragma unroll
    for (int mt=0;mt<4;++mt)
      #pragma unroll
      for (int nt=0;nt<4;++nt)
        sacc[mt][nt] = (f32x4){0.f,0.f,0.f,0.f};
    {
      bf16x8 aq[4], bk[4];
      #pragma unroll
      for (int mt=0;mt<4;++mt)
        aq[mt] = *(const bf16x8*)&slotA[(mt*16+rowa)*LDS_S + kg*8];
      #pragma unroll
      for (int nt=0;nt<4;++nt)
        bk[nt] = *(const bf16x8*)&slotB[(nt*16+rowa)*LDS_S + kg*8];
      __builtin_amdgcn_s_setprio(1);
      #pragma unroll
      for (int mt=0;mt<4;++mt)
        #pragma unroll
        for (int nt=0;nt<4;++nt)
          sacc[mt][nt] = __builtin_amdgcn_mfma_f32_16x16x32_bf16(aq[mt], bk[nt], sacc[mt][nt], 0, 0, 0);
      __builtin_amdgcn_s_setprio(0);
    }

    // ---- v -> vT [32][72] in slotB ----
    {
      f32x4 accv[4][2];
      #pragma unroll
      for (int mt=0;mt<4;++mt){ accv[mt][0]=(f32x4){0,0,0,0}; accv[mt][1]=(f32x4){0,0,0,0}; }
      #pragma unroll
      for (int kt=0;kt<8;++kt){
        bf16x8 av[4], bw[2];
        #pragma unroll
        for (int mt=0;mt<4;++mt)
          av[mt] = FRAG(shf, mt, 8, kt, ln);
        #pragma unroll
        for (int nt=0;nt<2;++nt)
          bw[nt] = WF(wqkv, 32 + tq + nt, 8, kt, ln);
        #pragma unroll
        for (int mt=0;mt<4;++mt)
          #pragma unroll
          for (int nt=0;nt<2;++nt)
            accv[mt][nt] = __builtin_amdgcn_mfma_f32_16x16x32_bf16(av[mt], bw[nt], accv[mt][nt], 0, 0, 0);
      }
      #pragma unroll
      for (int nt=0;nt<2;++nt){
        const float bias = inb[512 + hc + nt*16 + rowa];
        #pragma unroll
        for (int mt=0;mt<4;++mt)
          #pragma unroll
          for (int i=0;i<4;++i)
            slotB[(nt*16 + rowa)*LDVT + mt*16 + kg*4 + i] = f2bf(accv[mt][nt][i] + bias);
      }
    }

    // ---- softmax ----
    #pragma unroll
    for (int mt=0;mt<4;++mt){
      #pragma unroll
      for (int i=0;i<4;++i){
        float v0 = sacc[mt][0][i]*scale;
        float v1 = sacc[mt][1][i]*scale;
        float v2 = sacc[mt][2][i]*scale;
        float v3 = sacc[mt][3][i]*scale;
        float mx = fmaxf(fmaxf(v0,v1), fmaxf(v2,v3));
        #pragma unroll
        for (int d=1; d<16; d<<=1) mx = fmaxf(mx, __shfl_xor(mx, d, 64));
        v0 = __expf(v0-mx); v1 = __expf(v1-mx); v2 = __expf(v2-mx); v3 = __expf(v3-mx);
        float sm = v0+v1+v2+v3;
        #pragma unroll
        for (int d=1; d<16; d<<=1) sm += __shfl_xor(sm, d, 64);
        const float inv = 1.f / sm;
        sacc[mt][0][i] = v0*inv; sacc[mt][1][i] = v1*inv;
        sacc[mt][2][i] = v2*inv; sacc[mt][3][i] = v3*inv;
      }
    }

    // ---- PV in two kv-chunks of 32, P through slotA ----
    #pragma unroll
    for (int ck=0; ck<2; ++ck){
      #pragma unroll
      for (int ntl=0; ntl<2; ++ntl)
        #pragma unroll
        for (int mt=0;mt<4;++mt)
          #pragma unroll
          for (int i=0;i<4;++i)
            slotA[(mt*16 + kg*4 + i)*LDS_S + ntl*16 + rowa] = f2bf(sacc[mt][2*ck+ntl][i]);
      bf16x8 ap[4], bv[2];
      #pragma unroll
      for (int mt=0;mt<4;++mt)
        ap[mt] = *(const bf16x8*)&slotA[(mt*16+rowa)*LDS_S + kg*8];
      #pragma unroll
      for (int nt=0;nt<2;++nt)
        bv[nt] = *(const bf16x8*)&slotB[(nt*16+rowa)*LDVT + ck*32 + kg*8];
      __builtin_amdgcn_s_setprio(1);
      #pragma unroll
      for (int mt=0;mt<4;++mt)
        #pragma unroll
        for (int nt=0;nt<2;++nt)
          oacc[mt][hd*2+nt] = __builtin_amdgcn_mfma_f32_16x16x32_bf16(ap[mt], bv[nt], oacc[mt][hd*2+nt], 0, 0, 0);
      __builtin_amdgcn_s_setprio(0);
    }
  }

  __syncthreads();   // done with h (shf) & slots -> sh_o row-major o, xsh x-stash

  #pragma unroll
  for (int j=0;j<4;++j){
    const int col = wv*64 + j*16 + rowa;
    #pragma unroll
    for (int mt=0;mt<4;++mt)
      #pragma unroll
      for (int i=0;i<4;++i)
        sh_o[(mt*16 + kg*4 + i)*LDH + col] = f2bf(oacc[mt][j][i]);
  }
  {
    const int cbeg = wv*64;
    #pragma unroll
    for (int q=0;q<8;++q){
      bf16x8 pk;
      #pragma unroll
      for (int e=0;e<4;++e){
        const unsigned w = xpk[q*4+e];
        pk[2*e]   = (short)(w & 0xffffu);
        pk[2*e+1] = (short)(w >> 16);
      }
      *(bf16x8*)&xsh[ln*LDH + cbeg + q*8] = pk;
    }
  }
  __syncthreads();

  // ---- out-proj SWAPPED: D'[ch][tok] = wout x o^T; + bias + x residual(LDS) -> win2T ----
  {
    f32x4 acc[4][4];
    #pragma unroll
    for (int c0=0;c0<4;++c0)
      #pragma unroll
      for (int t0=0;t0<4;++t0)
        acc[c0][t0] = (f32x4){0.f,0.f,0.f,0.f};
    for (int kt=0; kt<8; ++kt){
      bf16x8 aw[4], bo[4];
      #pragma unroll
      for (int c0=0;c0<4;++c0)
        aw[c0] = WF(wout, wv*4 + c0, 8, kt, ln);
      #pragma unroll
      for (int t0=0;t0<4;++t0)
        bo[t0] = *(const bf16x8*)&sh_o[(t0*16+rowa)*LDH + kt*32 + kg*8];
      #pragma unroll
      for (int c0=0;c0<4;++c0)
        #pragma unroll
        for (int t0=0;t0<4;++t0)
          acc[c0][t0] = __builtin_amdgcn_mfma_f32_16x16x32_bf16(aw[c0], bo[t0], acc[c0][t0], 0, 0, 0);
    }
    #pragma unroll
    for (int c0=0;c0<4;++c0){
      #pragma unroll
      for (int i=0;i<4;++i){
        const int ch = wv*64 + c0*16 + kg*4 + i;
        const float bias = outb[ch];
        #pragma unroll
        for (int t0=0;t0<4;++t0){
          const int tok = t0*16 + rowa;
          const float res = bf2f(xsh[tok*LDH + ch]);
          win2T[(wi<<14) + ch*64 + tok] = f2bf(acc[c0][t0][i] + bias + res);
        }
      }
    }
  }
}

// ---------------- kernel 2: LN2 + half-chunk pipelined MLP (dbuf Mf, reg-prefetched weights) ----
// LDS (51200 B): Yf 32768 | Mf 2 x 8192 | red 2048. 2 waves/SIMD (reg budget 256).
#define K2_OFF_M   32768
#define K2_OFF_RED 49152
#define K2_SMEM    51200

// G1 step with preloaded w1 frag: acc1[ct] += aw x Y-token-tile(ct)
__device__ __forceinline__ void g1h_pre(const bf16x8 aw, const short* Yf,
                                        int kt, int ln, f32x4 acc1[4]){
  bf16x8 bh[4];
  #pragma unroll
  for (int ct=0;ct<4;++ct)
    bh[ct] = FRAG(Yf, ct, 8, kt, ln);
  #pragma unroll
  for (int ct=0;ct<4;++ct)
    acc1[ct] = __builtin_amdgcn_mfma_f32_16x16x32_bf16(aw, bh[ct], acc1[ct], 0, 0, 0);
}

// G2 step with preloaded w2 frags: acc2[c0][t0] += w2c[c0] x M frag
__device__ __forceinline__ void g2h_pre(const short* Mfb, const bf16x8* w2c4,
                                        int kt2, int ln, f32x4 acc2[4][4]){
  bf16x8 bm[4];
  #pragma unroll
  for (int t0=0;t0<4;++t0)
    bm[t0] = FRAG(Mfb, t0, 2, kt2, ln);
  #pragma unroll
  for (int c0=0;c0<4;++c0)
    #pragma unroll
    for (int t0=0;t0<4;++t0)
      acc2[c0][t0] = __builtin_amdgcn_mfma_f32_16x16x32_bf16(w2c4[c0], bm[t0], acc2[c0][t0], 0, 0, 0);
}

// GELU(acc1)+bias -> Mf frag-packed b64 writes (unchanged math/order)
__device__ __forceinline__ void gstore_h(short* Mfb, const float* __restrict__ b1,
                                         int c, int wv, int rowa, int kg,
                                         const f32x4 acc1[4]){
  const int hidb = c*64 + wv*16 + kg*4;
  const f32x4 b1v = *(const f32x4*)&b1[hidb];
  #pragma unroll
  for (int ct=0;ct<4;++ct){
    bf16x4 st;
    #pragma unroll
    for (int i=0;i<4;++i)
      st[i] = f2bf(gelu_f(acc1[ct][i] + b1v[i]));
    *(bf16x4*)&Mfb[(((ct*2 + (wv>>1))*64) + ((wv&1)*2 + (kg>>1))*16 + rowa)*8 + (kg&1)*4] = st;
  }
}

__global__ __launch_bounds__(256, 2)
void swin_mlp_kernel(const short* __restrict__ win2T,
                     const float* __restrict__ ln2w, const float* __restrict__ ln2b,
                     const float* __restrict__ b1,   const float* __restrict__ b2,
                     const short* __restrict__ w1,   const short* __restrict__ w2,
                     float* __restrict__ out)
{
  __shared__ char smem[K2_SMEM];
  short* Yf  = (short*)smem;
  short* Mf0 = (short*)(smem + K2_OFF_M);
  short* Mf1 = Mf0 + 4096;
  float* red_s  = (float*)(smem + K2_OFF_RED);
  float* red_q2 = red_s + 256;

  const int tid = threadIdx.x;
  const int wv  = tid >> 6;
  const int ln  = tid & 63;
  const int rowa = ln & 15;
  const int kg   = ln >> 4;

  const int bid = blockIdx.x;
  const int wi  = ((bid & 7) << 8) | (bid >> 3);   // XCD swizzle
  const int wb = wi << 14;

  // ---- LN2 from win2T (coalesced rows) -> Yf frag-packed ----
  {
    float vals[64];
    float s = 0.f, sq = 0.f;
    const int cbeg = wv*64;
    #pragma unroll
    for (int j=0;j<64;++j){
      float v = bf2f(win2T[wb + (cbeg + j)*64 + ln]);
      vals[j] = v; s += v; sq += v*v;
    }
    red_s[cbeg + ln]  = s;
    red_q2[cbeg + ln] = sq;
    __syncthreads();
    float sum = red_s[ln] + red_s[64+ln] + red_s[128+ln] + red_s[192+ln];
    float ssq = red_q2[ln] + red_q2[64+ln] + red_q2[128+ln] + red_q2[192+ln];
    float mean = sum * 0.00390625f;
    float var  = ssq * 0.00390625f - mean*mean;
    float rstd = rsqrtf(var + 1e-5f);
    const int ttile = ln >> 4;
    #pragma unroll
    for (int kl=0;kl<2;++kl){
      const int kt = wv*2 + kl;
      #pragma unroll
      for (int kgw=0;kgw<4;++kgw){
        bf16x8 pkv;
        #pragma unroll
        for (int e=0;e<8;++e){
          const int j = kl*32 + kgw*8 + e;
          const int c = cbeg + j;
          pkv[e] = f2bf((vals[j] - mean) * rstd * ln2w[c] + ln2b[c]);
        }
        *(bf16x8*)&Yf[(((ttile*8 + kt)*64) + kgw*16 + (ln & 15))*8] = pkv;
      }
    }
  }
  __syncthreads();

  // ---- half-chunk pipeline with register-prefetched weights ----
  f32x4 acc2[4][4];
  #pragma unroll
  for (int c0=0;c0<4;++c0)
    #pragma unroll
    for (int t0=0;t0<4;++t0)
      acc2[c0][t0] = (f32x4){0.f,0.f,0.f,0.f};

  // prologue: w1 frags for chunk 0, G1(0)
  bf16x8 w1c[8];
  #pragma unroll
  for (int kt=0;kt<8;++kt) w1c[kt] = WF(w1, 0*4 + wv, 8, kt, ln);
  f32x4 acc1[4];
  #pragma unroll
  for (int ct=0;ct<4;++ct) acc1[ct] = (f32x4){0.f,0.f,0.f,0.f};
  #pragma unroll
  for (int kt=0;kt<8;++kt) g1h_pre(w1c[kt], Yf, kt, ln, acc1);

  #pragma unroll
  for (int c = 0; c < 16; ++c){
    short* cur = (c & 1) ? Mf1 : Mf0;
    gstore_h(cur, b1, c, wv, rowa, kg, acc1);

    // issue THIS chunk's w2 frags + NEXT chunk's w1 frags before the barrier:
    // they ride out the barrier wait + G1 phase (loads have no LDS hazard).
    bf16x8 w2c[8];
    #pragma unroll
    for (int j=0;j<8;++j)
      w2c[j] = WF(w2, wv*4 + (j & 3), 32, c*2 + (j >> 2), ln);
    if (c < 15){
      #pragma unroll
      for (int kt=0;kt<8;++kt)
        w1c[kt] = WF(w1, (c+1)*4 + wv, 8, kt, ln);
    }
    __syncthreads();   // Mf(c) published

    if (c < 15){
      f32x4 acc1n[4];
      #pragma unroll
      for (int ct=0;ct<4;++ct) acc1n[ct] = (f32x4){0.f,0.f,0.f,0.f};
      #pragma unroll
      for (int kt=0;kt<4;++kt) g1h_pre(w1c[kt], Yf, kt, ln, acc1n);
      g2h_pre(cur, &w2c[0], 0, ln, acc2);
      #pragma unroll
      for (int kt=4;kt<8;++kt) g1h_pre(w1c[kt], Yf, kt, ln, acc1n);
      g2h_pre(cur, &w2c[4], 1, ln, acc2);
      #pragma unroll
      for (int ct=0;ct<4;++ct) acc1[ct] = acc1n[ct];
    } else {
      g2h_pre(cur, &w2c[0], 0, ln, acc2);
      g2h_pre(cur, &w2c[4], 1, ln, acc2);
    }
  }

  // ---- epilogue: D'[ch][tok]: + b2 + win2T residual (coalesced), coalesced NCHW store ----
  const int b  = wi >> 8;
  const int wh = (wi >> 4) & 15;
  const int ww = wi & 15;
  #pragma unroll
  for (int c0=0;c0<4;++c0){
    #pragma unroll
    for (int i=0;i<4;++i){
      const int ch = wv*64 + c0*16 + kg*4 + i;
      const float bias = b2[ch];
      #pragma unroll
      for (int t0=0;t0<4;++t0){
        const int tok = t0*16 + rowa;
        float v = acc2[c0][t0][i] + bias + bf2f(win2T[wb + ch*64 + tok]);
        const int r = tok >> 3, cw = tok & 7;
        const int hh = (wh*8 + r + 4) & 127;
        const int wcc = (ww*8 + cw + 4) & 127;
        out[(((b<<8) + ch) << 14) + hh*128 + wcc] = v;
      }
    }
  }
}

// ---------------- launch ----------------
extern "C" void kernel_launch(void* const* d_in, const int* in_sizes, int n_in,
                              void* d_out, int out_size, void* d_ws, size_t ws_size,
                              hipStream_t stream) {
  (void)in_sizes; (void)n_in; (void)out_size; (void)ws_size;
  const float* x    = (const float*)d_in[0];
  const float* ln1w = (const float*)d_in[1];
  const float* ln1b = (const float*)d_in[2];
  const float* inw  = (const float*)d_in[3];
  const float* inb  = (const float*)d_in[4];
  const float* outw = (const float*)d_in[5];
  const float* outb = (const float*)d_in[6];
  const float* ln2w = (const float*)d_in[7];
  const float* ln2b = (const float*)d_in[8];
  const float* w1f  = (const float*)d_in[9];
  const float* b1   = (const float*)d_in[10];
  const float* w2f  = (const float*)d_in[11];
  const float* b2   = (const float*)d_in[12];
  float* out = (float*)d_out;

  short* ws    = (short*)d_ws;
  short* wqkv  = ws;            // 768*256   (frag-packed, KT=8)
  short* wout  = ws + 196608;   // 256*256   (frag-packed, KT=8)
  short* w1b   = ws + 262144;   // 1024*256  (frag-packed, KT=8)
  short* w2b   = ws + 524288;   // 256*1024  (frag-packed, KT=32)
  short* win2T = ws + 786432;   // 2048 x 256ch x 64tok bf16

  hipLaunchKernelGGL(wpack_kernel, dim3(96),  dim3(256), 0, stream, inw,  wqkv, 256);
  hipLaunchKernelGGL(wpack_kernel, dim3(32),  dim3(256), 0, stream, outw, wout, 256);
  hipLaunchKernelGGL(wpack_kernel, dim3(128), dim3(256), 0, stream, w1f,  w1b,  256);
  hipLaunchKernelGGL(wpack_kernel, dim3(128), dim3(256), 0, stream, w2f,  w2b,  1024);

  hipLaunchKernelGGL(swin_attn_kernel, dim3(2048), dim3(256), 0, stream,
                     x, ln1w, ln1b, inb, outb, wqkv, wout, win2T);
  hipLaunchKernelGGL(swin_mlp_kernel, dim3(2048), dim3(256), 0, stream,
                     win2T, ln2w, ln2b, b1, b2, w1b, w2b, out);
}

// Round 14
// 414.335 us; speedup vs baseline: 1.3060x; 1.0417x over previous
//
#include <hip/hip_runtime.h>
#include <math.h>

// Swin block: B=8, C=256, H=W=128, WS=8, SS=4, NH=8, dh=32
// Weights frag-packed: wf[((tile*KT+kt)*64+l)*8+e] = W[tile*16+(l&15)][kt*32+(l>>4)*8+e]
// attn: x read once (reg stash), XCD swizzle, frag-packed h.
// mlp: half-chunk pipeline, dbuf Mf, reg-prefetched weights.
// r14: f2bf via native __bf16 cast (v_cvt_pk_bf16_f32); GELU tanh-form (no erff).

#define LDH 264   // bf16 row stride for row-major [64][256] tiles (o, xsh)
#define LDS_S 40  // per-wave q/k slots [64][40]
#define LDVT 72   // vT [32][72]

typedef __attribute__((ext_vector_type(8))) short bf16x8;
typedef __attribute__((ext_vector_type(4))) short bf16x4;
typedef __attribute__((ext_vector_type(4))) float f32x4;

#define WF(wf, tile, KT, kt, ln) (*(const bf16x8*)&(wf)[((((tile)*(KT)) + (kt))*64 + (ln))*8])
// frag-packed LDS tile (4 token-tiles x KT k-steps): FRAG(base, ttile, KT, kt, lane)
#define FRAG(basep, ttile, KT, kt, l) (*(const bf16x8*)&(basep)[((((ttile)*(KT)) + (kt))*64 + (l))*8])

static __device__ __forceinline__ float bf2f(short s){
  union { unsigned u; float f; } cv;
  cv.u = ((unsigned)(unsigned short)s) << 16;
  return cv.f;
}
// native bf16 convert (RNE; clang lowers to v_cvt_pk_bf16_f32)
static __device__ __forceinline__ short f2bf(float f){
  __bf16 h = (__bf16)f;
  union { __bf16 b; short s; } cv; cv.b = h;
  return cv.s;
}
// tanh-form GELU (max err ~3e-4, below bf16 quantization of m); NaN-safe at +-inf
static __device__ __forceinline__ float gelu_f(float x){
  const float u2 = 1.5957691216057308f * (x + 0.044715f * x * x * x);  // 2*sqrt(2/pi)*(...)
  const float e  = __expf(u2);
  const float t  = 1.f - 2.f / (e + 1.f);
  return 0.5f * x * (1.f + t);
}

// ---------------- K0: fp32 -> bf16 fragment-order repack ----------------
__global__ void wpack_kernel(const float* __restrict__ src, short* __restrict__ dst,
                             int K){
  const int t8 = blockIdx.x * 256 + threadIdx.x;
  const int e0 = t8 * 8;
  const int l   = (e0 >> 3) & 63;
  const int blk = e0 >> 9;
  const int KT  = K >> 5;
  const int kt   = blk % KT;
  const int tile = blk / KT;
  const int row = tile*16 + (l & 15);
  const int kb  = kt*32 + (l >> 4)*8;
  const float* s = src + row*K + kb;
  bf16x8 o;
  #pragma unroll
  for (int e=0;e<8;++e) o[e] = f2bf(s[e]);
  *(bf16x8*)&dst[e0] = o;
}

// ---------------- kernel 1: LN1 + QKV + attention + out-proj(swapped) -> win2T ----------------
#define K1_OFF_WV  33792
#define K1_OFF_RED 74752
#define K1_SMEM    76800

__global__ __launch_bounds__(256, 2)
void swin_attn_kernel(const float* __restrict__ x,
                      const float* __restrict__ ln1w, const float* __restrict__ ln1b,
                      const float* __restrict__ inb,  const float* __restrict__ outb,
                      const short* __restrict__ wqkv, const short* __restrict__ wout,
                      short* __restrict__ win2T)
{
  __shared__ char smem[K1_SMEM];
  short* shf    = (short*)smem;                 // h frag-packed (32768 B), then o row-major [64][264]
  short* sh_o   = (short*)smem;
  short* xsh    = (short*)(smem + K1_OFF_WV);   // x bf16 stash row-major (post-attention)
  float* red_s  = (float*)(smem + K1_OFF_RED);
  float* red_q2 = red_s + 256;

  const int tid = threadIdx.x;
  const int wv  = tid >> 6;
  const int ln  = tid & 63;
  const int rowa = ln & 15;
  const int kg   = ln >> 4;

  short* slotA = (short*)(smem + K1_OFF_WV) + wv*5120;
  short* slotB = slotA + 2560;

  const int bid = blockIdx.x;
  const int wi  = ((bid & 7) << 8) | (bid >> 3);   // XCD swizzle (2048%8==0, bijective)
  const int b  = wi >> 8;
  const int wh = (wi >> 4) & 15;
  const int ww = wi & 15;

  const int hh = (wh*8 + (ln >> 3) + 4) & 127;
  const int wc = (ww*8 + (ln & 7) + 4) & 127;
  const int offhw = hh*128 + wc;
  const int xbase = b << 22;

  unsigned xpk[32];
  {
    const int cbeg = wv*64;
    float vals[64];
    float s = 0.f, sq = 0.f;
    #pragma unroll
    for (int j = 0; j < 64; ++j){
      float v = x[xbase + ((cbeg + j) << 14) + offhw];
      vals[j] = v; s += v; sq += v*v;
    }
    #pragma unroll
    for (int p = 0; p < 32; ++p){
      const unsigned lo = (unsigned)(unsigned short)f2bf(vals[2*p]);
      const unsigned hi = (unsigned)(unsigned short)f2bf(vals[2*p+1]);
      xpk[p] = lo | (hi << 16);
    }
    red_s[cbeg + ln]  = s;
    red_q2[cbeg + ln] = sq;
    __syncthreads();
    float sum = red_s[ln] + red_s[64+ln] + red_s[128+ln] + red_s[192+ln];
    float ssq = red_q2[ln] + red_q2[64+ln] + red_q2[128+ln] + red_q2[192+ln];
    float mean = sum * 0.00390625f;
    float var  = ssq * 0.00390625f - mean*mean;
    float rstd = rsqrtf(var + 1e-5f);
    // h frag-packed write
    const int ttile = ln >> 4;
    #pragma unroll
    for (int kl=0;kl<2;++kl){
      const int kt = wv*2 + kl;
      #pragma unroll
      for (int kgw=0;kgw<4;++kgw){
        bf16x8 pkv;
        #pragma unroll
        for (int e=0;e<8;++e){
          const int j = kl*32 + kgw*8 + e;
          const int c = cbeg + j;
          pkv[e] = f2bf((vals[j] - mean) * rstd * ln1w[c] + ln1b[c]);
        }
        *(bf16x8*)&shf[(((ttile*8 + kt)*64) + kgw*16 + (ln & 15))*8] = pkv;
      }
    }
  }
  __syncthreads();

  const float scale = 0.1767766952966369f;
  f32x4 oacc[4][4];
  #pragma unroll
  for (int mt=0;mt<4;++mt)
    #pragma unroll
    for (int j=0;j<4;++j)
      oacc[mt][j] = (f32x4){0.f,0.f,0.f,0.f};

  #pragma unroll
  for (int hd = 0; hd < 2; ++hd){
    const int hc = (2*wv + hd) * 32;
    const int tq = (2*wv + hd) * 2;

    // ---- q + k fused (shared A-frags from frag-packed h) ----
    {
      f32x4 aq[4][2], ak[4][2];
      #pragma unroll
      for (int mt=0;mt<4;++mt){
        aq[mt][0]=(f32x4){0,0,0,0}; aq[mt][1]=(f32x4){0,0,0,0};
        ak[mt][0]=(f32x4){0,0,0,0}; ak[mt][1]=(f32x4){0,0,0,0};
      }
      #pragma unroll
      for (int kt=0;kt<8;++kt){
        bf16x8 av[4], bq[2], bk[2];
        #pragma unroll
        for (int mt=0;mt<4;++mt)
          av[mt] = FRAG(shf, mt, 8, kt, ln);
        #pragma unroll
        for (int nt=0;nt<2;++nt){
          bq[nt] = WF(wqkv, tq + nt,      8, kt, ln);
          bk[nt] = WF(wqkv, 16 + tq + nt, 8, kt, ln);
        }
        #pragma unroll
        for (int mt=0;mt<4;++mt)
          #pragma unroll
          for (int nt=0;nt<2;++nt){
            aq[mt][nt] = __builtin_amdgcn_mfma_f32_16x16x32_bf16(av[mt], bq[nt], aq[mt][nt], 0, 0, 0);
            ak[mt][nt] = __builtin_amdgcn_mfma_f32_16x16x32_bf16(av[mt], bk[nt], ak[mt][nt], 0, 0, 0);
          }
      }
      #pragma unroll
      for (int nt=0;nt<2;++nt){
        const float biasq = inb[hc + nt*16 + rowa];
        const float biask = inb[256 + hc + nt*16 + rowa];
        #pragma unroll
        for (int mt=0;mt<4;++mt)
          #pragma unroll
          for (int i=0;i<4;++i){
            slotA[(mt*16 + kg*4 + i)*LDS_S + nt*16 + rowa] = f2bf(aq[mt][nt][i] + biasq);
            slotB[(mt*16 + kg*4 + i)*LDS_S + nt*16 + rowa] = f2bf(ak[mt][nt][i] + biask);
          }
      }
    }

    // ---- S = q @ k^T ----
    f32x4 sacc[4][4];
    #pragma unroll
    for (int mt=0;mt<4;++mt)
      #pragma unroll
      for (int nt=0;nt<4;++nt)
        sacc[mt][nt] = (f32x4){0.f,0.f,0.f,0.f};
    {
      bf16x8 aq[4], bk[4];
      #pragma unroll
      for (int mt=0;mt<4;++mt)
        aq[mt] = *(const bf16x8*)&slotA[(mt*16+rowa)*LDS_S + kg*8];
      #pragma unroll
      for (int nt=0;nt<4;++nt)
        bk[nt] = *(const bf16x8*)&slotB[(nt*16+rowa)*LDS_S + kg*8];
      __builtin_amdgcn_s_setprio(1);
      #pragma unroll
      for (int mt=0;mt<4;++mt)
        #pragma unroll
        for (int nt=0;nt<4;++nt)
          sacc[mt][nt] = __builtin_amdgcn_mfma_f32_16x16x32_bf16(aq[mt], bk[nt], sacc[mt][nt], 0, 0, 0);
      __builtin_amdgcn_s_setprio(0);
    }

    // ---- v -> vT [32][72] in slotB ----
    {
      f32x4 accv[4][2];
      #pragma unroll
      for (int mt=0;mt<4;++mt){ accv[mt][0]=(f32x4){0,0,0,0}; accv[mt][1]=(f32x4){0,0,0,0}; }
      #pragma unroll
      for (int kt=0;kt<8;++kt){
        bf16x8 av[4], bw[2];
        #pragma unroll
        for (int mt=0;mt<4;++mt)
          av[mt] = FRAG(shf, mt, 8, kt, ln);
        #pragma unroll
        for (int nt=0;nt<2;++nt)
          bw[nt] = WF(wqkv, 32 + tq + nt, 8, kt, ln);
        #pragma unroll
        for (int mt=0;mt<4;++mt)
          #pragma unroll
          for (int nt=0;nt<2;++nt)
            accv[mt][nt] = __builtin_amdgcn_mfma_f32_16x16x32_bf16(av[mt], bw[nt], accv[mt][nt], 0, 0, 0);
      }
      #pragma unroll
      for (int nt=0;nt<2;++nt){
        const float bias = inb[512 + hc + nt*16 + rowa];
        #pragma unroll
        for (int mt=0;mt<4;++mt)
          #pragma unroll
          for (int i=0;i<4;++i)
            slotB[(nt*16 + rowa)*LDVT + mt*16 + kg*4 + i] = f2bf(accv[mt][nt][i] + bias);
      }
    }

    // ---- softmax ----
    #pragma unroll
    for (int mt=0;mt<4;++mt){
      #pragma unroll
      for (int i=0;i<4;++i){
        float v0 = sacc[mt][0][i]*scale;
        float v1 = sacc[mt][1][i]*scale;
        float v2 = sacc[mt][2][i]*scale;
        float v3 = sacc[mt][3][i]*scale;
        float mx = fmaxf(fmaxf(v0,v1), fmaxf(v2,v3));
        #pragma unroll
        for (int d=1; d<16; d<<=1) mx = fmaxf(mx, __shfl_xor(mx, d, 64));
        v0 = __expf(v0-mx); v1 = __expf(v1-mx); v2 = __expf(v2-mx); v3 = __expf(v3-mx);
        float sm = v0+v1+v2+v3;
        #pragma unroll
        for (int d=1; d<16; d<<=1) sm += __shfl_xor(sm, d, 64);
        const float inv = 1.f / sm;
        sacc[mt][0][i] = v0*inv; sacc[mt][1][i] = v1*inv;
        sacc[mt][2][i] = v2*inv; sacc[mt][3][i] = v3*inv;
      }
    }

    // ---- PV in two kv-chunks of 32, P through slotA ----
    #pragma unroll
    for (int ck=0; ck<2; ++ck){
      #pragma unroll
      for (int ntl=0; ntl<2; ++ntl)
        #pragma unroll
        for (int mt=0;mt<4;++mt)
          #pragma unroll
          for (int i=0;i<4;++i)
            slotA[(mt*16 + kg*4 + i)*LDS_S + ntl*16 + rowa] = f2bf(sacc[mt][2*ck+ntl][i]);
      bf16x8 ap[4], bv[2];
      #pragma unroll
      for (int mt=0;mt<4;++mt)
        ap[mt] = *(const bf16x8*)&slotA[(mt*16+rowa)*LDS_S + kg*8];
      #pragma unroll
      for (int nt=0;nt<2;++nt)
        bv[nt] = *(const bf16x8*)&slotB[(nt*16+rowa)*LDVT + ck*32 + kg*8];
      __builtin_amdgcn_s_setprio(1);
      #pragma unroll
      for (int mt=0;mt<4;++mt)
        #pragma unroll
        for (int nt=0;nt<2;++nt)
          oacc[mt][hd*2+nt] = __builtin_amdgcn_mfma_f32_16x16x32_bf16(ap[mt], bv[nt], oacc[mt][hd*2+nt], 0, 0, 0);
      __builtin_amdgcn_s_setprio(0);
    }
  }

  __syncthreads();   // done with h (shf) & slots -> sh_o row-major o, xsh x-stash

  #pragma unroll
  for (int j=0;j<4;++j){
    const int col = wv*64 + j*16 + rowa;
    #pragma unroll
    for (int mt=0;mt<4;++mt)
      #pragma unroll
      for (int i=0;i<4;++i)
        sh_o[(mt*16 + kg*4 + i)*LDH + col] = f2bf(oacc[mt][j][i]);
  }
  {
    const int cbeg = wv*64;
    #pragma unroll
    for (int q=0;q<8;++q){
      bf16x8 pk;
      #pragma unroll
      for (int e=0;e<4;++e){
        const unsigned w = xpk[q*4+e];
        pk[2*e]   = (short)(w & 0xffffu);
        pk[2*e+1] = (short)(w >> 16);
      }
      *(bf16x8*)&xsh[ln*LDH + cbeg + q*8] = pk;
    }
  }
  __syncthreads();

  // ---- out-proj SWAPPED: D'[ch][tok] = wout x o^T; + bias + x residual(LDS) -> win2T ----
  {
    f32x4 acc[4][4];
    #pragma unroll
    for (int c0=0;c0<4;++c0)
      #pragma unroll
      for (int t0=0;t0<4;++t0)
        acc[c0][t0] = (f32x4){0.f,0.f,0.f,0.f};
    for (int kt=0; kt<8; ++kt){
      bf16x8 aw[4], bo[4];
      #pragma unroll
      for (int c0=0;c0<4;++c0)
        aw[c0] = WF(wout, wv*4 + c0, 8, kt, ln);
      #pragma unroll
      for (int t0=0;t0<4;++t0)
        bo[t0] = *(const bf16x8*)&sh_o[(t0*16+rowa)*LDH + kt*32 + kg*8];
      #pragma unroll
      for (int c0=0;c0<4;++c0)
        #pragma unroll
        for (int t0=0;t0<4;++t0)
          acc[c0][t0] = __builtin_amdgcn_mfma_f32_16x16x32_bf16(aw[c0], bo[t0], acc[c0][t0], 0, 0, 0);
    }
    #pragma unroll
    for (int c0=0;c0<4;++c0){
      #pragma unroll
      for (int i=0;i<4;++i){
        const int ch = wv*64 + c0*16 + kg*4 + i;
        const float bias = outb[ch];
        #pragma unroll
        for (int t0=0;t0<4;++t0){
          const int tok = t0*16 + rowa;
          const float res = bf2f(xsh[tok*LDH + ch]);
          win2T[(wi<<14) + ch*64 + tok] = f2bf(acc[c0][t0][i] + bias + res);
        }
      }
    }
  }
}

// ---------------- kernel 2: LN2 + half-chunk pipelined MLP (dbuf Mf, reg-prefetched weights) ----
// LDS (51200 B): Yf 32768 | Mf 2 x 8192 | red 2048. 2 waves/SIMD (reg budget 256).
#define K2_OFF_M   32768
#define K2_OFF_RED 49152
#define K2_SMEM    51200

// G1 step with preloaded w1 frag: acc1[ct] += aw x Y-token-tile(ct)
__device__ __forceinline__ void g1h_pre(const bf16x8 aw, const short* Yf,
                                        int kt, int ln, f32x4 acc1[4]){
  bf16x8 bh[4];
  #pragma unroll
  for (int ct=0;ct<4;++ct)
    bh[ct] = FRAG(Yf, ct, 8, kt, ln);
  #pragma unroll
  for (int ct=0;ct<4;++ct)
    acc1[ct] = __builtin_amdgcn_mfma_f32_16x16x32_bf16(aw, bh[ct], acc1[ct], 0, 0, 0);
}

// G2 step with preloaded w2 frags: acc2[c0][t0] += w2c[c0] x M frag
__device__ __forceinline__ void g2h_pre(const short* Mfb, const bf16x8* w2c4,
                                        int kt2, int ln, f32x4 acc2[4][4]){
  bf16x8 bm[4];
  #pragma unroll
  for (int t0=0;t0<4;++t0)
    bm[t0] = FRAG(Mfb, t0, 2, kt2, ln);
  #pragma unroll
  for (int c0=0;c0<4;++c0)
    #pragma unroll
    for (int t0=0;t0<4;++t0)
      acc2[c0][t0] = __builtin_amdgcn_mfma_f32_16x16x32_bf16(w2c4[c0], bm[t0], acc2[c0][t0], 0, 0, 0);
}

// GELU(acc1)+bias -> Mf frag-packed b64 writes (tanh-form gelu)
__device__ __forceinline__ void gstore_h(short* Mfb, const float* __restrict__ b1,
                                         int c, int wv, int rowa, int kg,
                                         const f32x4 acc1[4]){
  const int hidb = c*64 + wv*16 + kg*4;
  const f32x4 b1v = *(const f32x4*)&b1[hidb];
  #pragma unroll
  for (int ct=0;ct<4;++ct){
    bf16x4 st;
    #pragma unroll
    for (int i=0;i<4;++i)
      st[i] = f2bf(gelu_f(acc1[ct][i] + b1v[i]));
    *(bf16x4*)&Mfb[(((ct*2 + (wv>>1))*64) + ((wv&1)*2 + (kg>>1))*16 + rowa)*8 + (kg&1)*4] = st;
  }
}

__global__ __launch_bounds__(256, 2)
void swin_mlp_kernel(const short* __restrict__ win2T,
                     const float* __restrict__ ln2w, const float* __restrict__ ln2b,
                     const float* __restrict__ b1,   const float* __restrict__ b2,
                     const short* __restrict__ w1,   const short* __restrict__ w2,
                     float* __restrict__ out)
{
  __shared__ char smem[K2_SMEM];
  short* Yf  = (short*)smem;
  short* Mf0 = (short*)(smem + K2_OFF_M);
  short* Mf1 = Mf0 + 4096;
  float* red_s  = (float*)(smem + K2_OFF_RED);
  float* red_q2 = red_s + 256;

  const int tid = threadIdx.x;
  const int wv  = tid >> 6;
  const int ln  = tid & 63;
  const int rowa = ln & 15;
  const int kg   = ln >> 4;

  const int bid = blockIdx.x;
  const int wi  = ((bid & 7) << 8) | (bid >> 3);   // XCD swizzle
  const int wb = wi << 14;

  // ---- LN2 from win2T (coalesced rows) -> Yf frag-packed ----
  {
    float vals[64];
    float s = 0.f, sq = 0.f;
    const int cbeg = wv*64;
    #pragma unroll
    for (int j=0;j<64;++j){
      float v = bf2f(win2T[wb + (cbeg + j)*64 + ln]);
      vals[j] = v; s += v; sq += v*v;
    }
    red_s[cbeg + ln]  = s;
    red_q2[cbeg + ln] = sq;
    __syncthreads();
    float sum = red_s[ln] + red_s[64+ln] + red_s[128+ln] + red_s[192+ln];
    float ssq = red_q2[ln] + red_q2[64+ln] + red_q2[128+ln] + red_q2[192+ln];
    float mean = sum * 0.00390625f;
    float var  = ssq * 0.00390625f - mean*mean;
    float rstd = rsqrtf(var + 1e-5f);
    const int ttile = ln >> 4;
    #pragma unroll
    for (int kl=0;kl<2;++kl){
      const int kt = wv*2 + kl;
      #pragma unroll
      for (int kgw=0;kgw<4;++kgw){
        bf16x8 pkv;
        #pragma unroll
        for (int e=0;e<8;++e){
          const int j = kl*32 + kgw*8 + e;
          const int c = cbeg + j;
          pkv[e] = f2bf((vals[j] - mean) * rstd * ln2w[c] + ln2b[c]);
        }
        *(bf16x8*)&Yf[(((ttile*8 + kt)*64) + kgw*16 + (ln & 15))*8] = pkv;
      }
    }
  }
  __syncthreads();

  // ---- half-chunk pipeline with register-prefetched weights ----
  f32x4 acc2[4][4];
  #pragma unroll
  for (int c0=0;c0<4;++c0)
    #pragma unroll
    for (int t0=0;t0<4;++t0)
      acc2[c0][t0] = (f32x4){0.f,0.f,0.f,0.f};

  // prologue: w1 frags for chunk 0, G1(0)
  bf16x8 w1c[8];
  #pragma unroll
  for (int kt=0;kt<8;++kt) w1c[kt] = WF(w1, 0*4 + wv, 8, kt, ln);
  f32x4 acc1[4];
  #pragma unroll
  for (int ct=0;ct<4;++ct) acc1[ct] = (f32x4){0.f,0.f,0.f,0.f};
  #pragma unroll
  for (int kt=0;kt<8;++kt) g1h_pre(w1c[kt], Yf, kt, ln, acc1);

  #pragma unroll
  for (int c = 0; c < 16; ++c){
    short* cur = (c & 1) ? Mf1 : Mf0;
    gstore_h(cur, b1, c, wv, rowa, kg, acc1);

    // issue THIS chunk's w2 frags + NEXT chunk's w1 frags before the barrier
    bf16x8 w2c[8];
    #pragma unroll
    for (int j=0;j<8;++j)
      w2c[j] = WF(w2, wv*4 + (j & 3), 32, c*2 + (j >> 2), ln);
    if (c < 15){
      #pragma unroll
      for (int kt=0;kt<8;++kt)
        w1c[kt] = WF(w1, (c+1)*4 + wv, 8, kt, ln);
    }
    __syncthreads();   // Mf(c) published

    if (c < 15){
      f32x4 acc1n[4];
      #pragma unroll
      for (int ct=0;ct<4;++ct) acc1n[ct] = (f32x4){0.f,0.f,0.f,0.f};
      #pragma unroll
      for (int kt=0;kt<4;++kt) g1h_pre(w1c[kt], Yf, kt, ln, acc1n);
      g2h_pre(cur, &w2c[0], 0, ln, acc2);
      #pragma unroll
      for (int kt=4;kt<8;++kt) g1h_pre(w1c[kt], Yf, kt, ln, acc1n);
      g2h_pre(cur, &w2c[4], 1, ln, acc2);
      #pragma unroll
      for (int ct=0;ct<4;++ct) acc1[ct] = acc1n[ct];
    } else {
      g2h_pre(cur, &w2c[0], 0, ln, acc2);
      g2h_pre(cur, &w2c[4], 1, ln, acc2);
    }
  }

  // ---- epilogue: D'[ch][tok]: + b2 + win2T residual (coalesced), coalesced NCHW store ----
  const int b  = wi >> 8;
  const int wh = (wi >> 4) & 15;
  const int ww = wi & 15;
  #pragma unroll
  for (int c0=0;c0<4;++c0){
    #pragma unroll
    for (int i=0;i<4;++i){
      const int ch = wv*64 + c0*16 + kg*4 + i;
      const float bias = b2[ch];
      #pragma unroll
      for (int t0=0;t0<4;++t0){
        const int tok = t0*16 + rowa;
        float v = acc2[c0][t0][i] + bias + bf2f(win2T[wb + ch*64 + tok]);
        const int r = tok >> 3, cw = tok & 7;
        const int hh = (wh*8 + r + 4) & 127;
        const int wcc = (ww*8 + cw + 4) & 127;
        out[(((b<<8) + ch) << 14) + hh*128 + wcc] = v;
      }
    }
  }
}

// ---------------- launch ----------------
extern "C" void kernel_launch(void* const* d_in, const int* in_sizes, int n_in,
                              void* d_out, int out_size, void* d_ws, size_t ws_size,
                              hipStream_t stream) {
  (void)in_sizes; (void)n_in; (void)out_size; (void)ws_size;
  const float* x    = (const float*)d_in[0];
  const float* ln1w = (const float*)d_in[1];
  const float* ln1b = (const float*)d_in[2];
  const float* inw  = (const float*)d_in[3];
  const float* inb  = (const float*)d_in[4];
  const float* outw = (const float*)d_in[5];
  const float* outb = (const float*)d_in[6];
  const float* ln2w = (const float*)d_in[7];
  const float* ln2b = (const float*)d_in[8];
  const float* w1f  = (const float*)d_in[9];
  const float* b1   = (const float*)d_in[10];
  const float* w2f  = (const float*)d_in[11];
  const float* b2   = (const float*)d_in[12];
  float* out = (float*)d_out;

  short* ws    = (short*)d_ws;
  short* wqkv  = ws;            // 768*256   (frag-packed, KT=8)
  short* wout  = ws + 196608;   // 256*256   (frag-packed, KT=8)
  short* w1b   = ws + 262144;   // 1024*256  (frag-packed, KT=8)
  short* w2b   = ws + 524288;   // 256*1024  (frag-packed, KT=32)
  short* win2T = ws + 786432;   // 2048 x 256ch x 64tok bf16

  hipLaunchKernelGGL(wpack_kernel, dim3(96),  dim3(256), 0, stream, inw,  wqkv, 256);
  hipLaunchKernelGGL(wpack_kernel, dim3(32),  dim3(256), 0, stream, outw, wout, 256);
  hipLaunchKernelGGL(wpack_kernel, dim3(128), dim3(256), 0, stream, w1f,  w1b,  256);
  hipLaunchKernelGGL(wpack_kernel, dim3(128), dim3(256), 0, stream, w2f,  w2b,  1024);

  hipLaunchKernelGGL(swin_attn_kernel, dim3(2048), dim3(256), 0, stream,
                     x, ln1w, ln1b, inb, outb, wqkv, wout, win2T);
  hipLaunchKernelGGL(swin_mlp_kernel, dim3(2048), dim3(256), 0, stream,
                     win2T, ln2w, ln2b, b1, b2, w1b, w2b, out);
}

// Round 15
// 411.614 us; speedup vs baseline: 1.3146x; 1.0066x over previous
//
#include <hip/hip_runtime.h>
#include <math.h>

// Swin block: B=8, C=256, H=W=128, WS=8, SS=4, NH=8, dh=32
// Weights frag-packed: wf[((tile*KT+kt)*64+l)*8+e] = W[tile*16+(l&15)][kt*32+(l>>4)*8+e]
// attn: x read once (reg stash), XCD swizzle, frag-packed h.
// mlp: half-chunk pipeline, dbuf Mf, reduced reg prefetch (w1c[4]+w2c[8]) to fit
//      unified regs <= 170 -> 3 waves/SIMD with prefetch intact.

#define LDH 264   // bf16 row stride for row-major [64][256] tiles (o, xsh)
#define LDS_S 40  // per-wave q/k slots [64][40]
#define LDVT 72   // vT [32][72]

typedef __attribute__((ext_vector_type(8))) short bf16x8;
typedef __attribute__((ext_vector_type(4))) short bf16x4;
typedef __attribute__((ext_vector_type(4))) float f32x4;

#define WF(wf, tile, KT, kt, ln) (*(const bf16x8*)&(wf)[((((tile)*(KT)) + (kt))*64 + (ln))*8])
// frag-packed LDS tile (4 token-tiles x KT k-steps): FRAG(base, ttile, KT, kt, lane)
#define FRAG(basep, ttile, KT, kt, l) (*(const bf16x8*)&(basep)[((((ttile)*(KT)) + (kt))*64 + (l))*8])

static __device__ __forceinline__ float bf2f(short s){
  union { unsigned u; float f; } cv;
  cv.u = ((unsigned)(unsigned short)s) << 16;
  return cv.f;
}
// native bf16 convert (RNE; clang lowers to v_cvt_pk_bf16_f32)
static __device__ __forceinline__ short f2bf(float f){
  __bf16 h = (__bf16)f;
  union { __bf16 b; short s; } cv; cv.b = h;
  return cv.s;
}
// tanh-form GELU (max err ~3e-4, below bf16 quantization of m); NaN-safe at +-inf
static __device__ __forceinline__ float gelu_f(float x){
  const float u2 = 1.5957691216057308f * (x + 0.044715f * x * x * x);  // 2*sqrt(2/pi)*(...)
  const float e  = __expf(u2);
  const float t  = 1.f - 2.f / (e + 1.f);
  return 0.5f * x * (1.f + t);
}

// ---------------- K0: fp32 -> bf16 fragment-order repack ----------------
__global__ void wpack_kernel(const float* __restrict__ src, short* __restrict__ dst,
                             int K){
  const int t8 = blockIdx.x * 256 + threadIdx.x;
  const int e0 = t8 * 8;
  const int l   = (e0 >> 3) & 63;
  const int blk = e0 >> 9;
  const int KT  = K >> 5;
  const int kt   = blk % KT;
  const int tile = blk / KT;
  const int row = tile*16 + (l & 15);
  const int kb  = kt*32 + (l >> 4)*8;
  const float* s = src + row*K + kb;
  bf16x8 o;
  #pragma unroll
  for (int e=0;e<8;++e) o[e] = f2bf(s[e]);
  *(bf16x8*)&dst[e0] = o;
}

// ---------------- kernel 1: LN1 + QKV + attention + out-proj(swapped) -> win2T ----------------
#define K1_OFF_WV  33792
#define K1_OFF_RED 74752
#define K1_SMEM    76800

__global__ __launch_bounds__(256, 2)
void swin_attn_kernel(const float* __restrict__ x,
                      const float* __restrict__ ln1w, const float* __restrict__ ln1b,
                      const float* __restrict__ inb,  const float* __restrict__ outb,
                      const short* __restrict__ wqkv, const short* __restrict__ wout,
                      short* __restrict__ win2T)
{
  __shared__ char smem[K1_SMEM];
  short* shf    = (short*)smem;                 // h frag-packed (32768 B), then o row-major [64][264]
  short* sh_o   = (short*)smem;
  short* xsh    = (short*)(smem + K1_OFF_WV);   // x bf16 stash row-major (post-attention)
  float* red_s  = (float*)(smem + K1_OFF_RED);
  float* red_q2 = red_s + 256;

  const int tid = threadIdx.x;
  const int wv  = tid >> 6;
  const int ln  = tid & 63;
  const int rowa = ln & 15;
  const int kg   = ln >> 4;

  short* slotA = (short*)(smem + K1_OFF_WV) + wv*5120;
  short* slotB = slotA + 2560;

  const int bid = blockIdx.x;
  const int wi  = ((bid & 7) << 8) | (bid >> 3);   // XCD swizzle (2048%8==0, bijective)
  const int b  = wi >> 8;
  const int wh = (wi >> 4) & 15;
  const int ww = wi & 15;

  const int hh = (wh*8 + (ln >> 3) + 4) & 127;
  const int wc = (ww*8 + (ln & 7) + 4) & 127;
  const int offhw = hh*128 + wc;
  const int xbase = b << 22;

  unsigned xpk[32];
  {
    const int cbeg = wv*64;
    float vals[64];
    float s = 0.f, sq = 0.f;
    #pragma unroll
    for (int j = 0; j < 64; ++j){
      float v = x[xbase + ((cbeg + j) << 14) + offhw];
      vals[j] = v; s += v; sq += v*v;
    }
    #pragma unroll
    for (int p = 0; p < 32; ++p){
      const unsigned lo = (unsigned)(unsigned short)f2bf(vals[2*p]);
      const unsigned hi = (unsigned)(unsigned short)f2bf(vals[2*p+1]);
      xpk[p] = lo | (hi << 16);
    }
    red_s[cbeg + ln]  = s;
    red_q2[cbeg + ln] = sq;
    __syncthreads();
    float sum = red_s[ln] + red_s[64+ln] + red_s[128+ln] + red_s[192+ln];
    float ssq = red_q2[ln] + red_q2[64+ln] + red_q2[128+ln] + red_q2[192+ln];
    float mean = sum * 0.00390625f;
    float var  = ssq * 0.00390625f - mean*mean;
    float rstd = rsqrtf(var + 1e-5f);
    // h frag-packed write
    const int ttile = ln >> 4;
    #pragma unroll
    for (int kl=0;kl<2;++kl){
      const int kt = wv*2 + kl;
      #pragma unroll
      for (int kgw=0;kgw<4;++kgw){
        bf16x8 pkv;
        #pragma unroll
        for (int e=0;e<8;++e){
          const int j = kl*32 + kgw*8 + e;
          const int c = cbeg + j;
          pkv[e] = f2bf((vals[j] - mean) * rstd * ln1w[c] + ln1b[c]);
        }
        *(bf16x8*)&shf[(((ttile*8 + kt)*64) + kgw*16 + (ln & 15))*8] = pkv;
      }
    }
  }
  __syncthreads();

  const float scale = 0.1767766952966369f;
  f32x4 oacc[4][4];
  #pragma unroll
  for (int mt=0;mt<4;++mt)
    #pragma unroll
    for (int j=0;j<4;++j)
      oacc[mt][j] = (f32x4){0.f,0.f,0.f,0.f};

  #pragma unroll
  for (int hd = 0; hd < 2; ++hd){
    const int hc = (2*wv + hd) * 32;
    const int tq = (2*wv + hd) * 2;

    // ---- q + k fused (shared A-frags from frag-packed h) ----
    {
      f32x4 aq[4][2], ak[4][2];
      #pragma unroll
      for (int mt=0;mt<4;++mt){
        aq[mt][0]=(f32x4){0,0,0,0}; aq[mt][1]=(f32x4){0,0,0,0};
        ak[mt][0]=(f32x4){0,0,0,0}; ak[mt][1]=(f32x4){0,0,0,0};
      }
      #pragma unroll
      for (int kt=0;kt<8;++kt){
        bf16x8 av[4], bq[2], bk[2];
        #pragma unroll
        for (int mt=0;mt<4;++mt)
          av[mt] = FRAG(shf, mt, 8, kt, ln);
        #pragma unroll
        for (int nt=0;nt<2;++nt){
          bq[nt] = WF(wqkv, tq + nt,      8, kt, ln);
          bk[nt] = WF(wqkv, 16 + tq + nt, 8, kt, ln);
        }
        #pragma unroll
        for (int mt=0;mt<4;++mt)
          #pragma unroll
          for (int nt=0;nt<2;++nt){
            aq[mt][nt] = __builtin_amdgcn_mfma_f32_16x16x32_bf16(av[mt], bq[nt], aq[mt][nt], 0, 0, 0);
            ak[mt][nt] = __builtin_amdgcn_mfma_f32_16x16x32_bf16(av[mt], bk[nt], ak[mt][nt], 0, 0, 0);
          }
      }
      #pragma unroll
      for (int nt=0;nt<2;++nt){
        const float biasq = inb[hc + nt*16 + rowa];
        const float biask = inb[256 + hc + nt*16 + rowa];
        #pragma unroll
        for (int mt=0;mt<4;++mt)
          #pragma unroll
          for (int i=0;i<4;++i){
            slotA[(mt*16 + kg*4 + i)*LDS_S + nt*16 + rowa] = f2bf(aq[mt][nt][i] + biasq);
            slotB[(mt*16 + kg*4 + i)*LDS_S + nt*16 + rowa] = f2bf(ak[mt][nt][i] + biask);
          }
      }
    }

    // ---- S = q @ k^T ----
    f32x4 sacc[4][4];
    #pragma unroll
    for (int mt=0;mt<4;++mt)
      #pragma unroll
      for (int nt=0;nt<4;++nt)
        sacc[mt][nt] = (f32x4){0.f,0.f,0.f,0.f};
    {
      bf16x8 aq[4], bk[4];
      #pragma unroll
      for (int mt=0;mt<4;++mt)
        aq[mt] = *(const bf16x8*)&slotA[(mt*16+rowa)*LDS_S + kg*8];
      #pragma unroll
      for (int nt=0;nt<4;++nt)
        bk[nt] = *(const bf16x8*)&slotB[(nt*16+rowa)*LDS_S + kg*8];
      __builtin_amdgcn_s_setprio(1);
      #pragma unroll
      for (int mt=0;mt<4;++mt)
        #pragma unroll
        for (int nt=0;nt<4;++nt)
          sacc[mt][nt] = __builtin_amdgcn_mfma_f32_16x16x32_bf16(aq[mt], bk[nt], sacc[mt][nt], 0, 0, 0);
      __builtin_amdgcn_s_setprio(0);
    }

    // ---- v -> vT [32][72] in slotB ----
    {
      f32x4 accv[4][2];
      #pragma unroll
      for (int mt=0;mt<4;++mt){ accv[mt][0]=(f32x4){0,0,0,0}; accv[mt][1]=(f32x4){0,0,0,0}; }
      #pragma unroll
      for (int kt=0;kt<8;++kt){
        bf16x8 av[4], bw[2];
        #pragma unroll
        for (int mt=0;mt<4;++mt)
          av[mt] = FRAG(shf, mt, 8, kt, ln);
        #pragma unroll
        for (int nt=0;nt<2;++nt)
          bw[nt] = WF(wqkv, 32 + tq + nt, 8, kt, ln);
        #pragma unroll
        for (int mt=0;mt<4;++mt)
          #pragma unroll
          for (int nt=0;nt<2;++nt)
            accv[mt][nt] = __builtin_amdgcn_mfma_f32_16x16x32_bf16(av[mt], bw[nt], accv[mt][nt], 0, 0, 0);
      }
      #pragma unroll
      for (int nt=0;nt<2;++nt){
        const float bias = inb[512 + hc + nt*16 + rowa];
        #pragma unroll
        for (int mt=0;mt<4;++mt)
          #pragma unroll
          for (int i=0;i<4;++i)
            slotB[(nt*16 + rowa)*LDVT + mt*16 + kg*4 + i] = f2bf(accv[mt][nt][i] + bias);
      }
    }

    // ---- softmax ----
    #pragma unroll
    for (int mt=0;mt<4;++mt){
      #pragma unroll
      for (int i=0;i<4;++i){
        float v0 = sacc[mt][0][i]*scale;
        float v1 = sacc[mt][1][i]*scale;
        float v2 = sacc[mt][2][i]*scale;
        float v3 = sacc[mt][3][i]*scale;
        float mx = fmaxf(fmaxf(v0,v1), fmaxf(v2,v3));
        #pragma unroll
        for (int d=1; d<16; d<<=1) mx = fmaxf(mx, __shfl_xor(mx, d, 64));
        v0 = __expf(v0-mx); v1 = __expf(v1-mx); v2 = __expf(v2-mx); v3 = __expf(v3-mx);
        float sm = v0+v1+v2+v3;
        #pragma unroll
        for (int d=1; d<16; d<<=1) sm += __shfl_xor(sm, d, 64);
        const float inv = 1.f / sm;
        sacc[mt][0][i] = v0*inv; sacc[mt][1][i] = v1*inv;
        sacc[mt][2][i] = v2*inv; sacc[mt][3][i] = v3*inv;
      }
    }

    // ---- PV in two kv-chunks of 32, P through slotA ----
    #pragma unroll
    for (int ck=0; ck<2; ++ck){
      #pragma unroll
      for (int ntl=0; ntl<2; ++ntl)
        #pragma unroll
        for (int mt=0;mt<4;++mt)
          #pragma unroll
          for (int i=0;i<4;++i)
            slotA[(mt*16 + kg*4 + i)*LDS_S + ntl*16 + rowa] = f2bf(sacc[mt][2*ck+ntl][i]);
      bf16x8 ap[4], bv[2];
      #pragma unroll
      for (int mt=0;mt<4;++mt)
        ap[mt] = *(const bf16x8*)&slotA[(mt*16+rowa)*LDS_S + kg*8];
      #pragma unroll
      for (int nt=0;nt<2;++nt)
        bv[nt] = *(const bf16x8*)&slotB[(nt*16+rowa)*LDVT + ck*32 + kg*8];
      __builtin_amdgcn_s_setprio(1);
      #pragma unroll
      for (int mt=0;mt<4;++mt)
        #pragma unroll
        for (int nt=0;nt<2;++nt)
          oacc[mt][hd*2+nt] = __builtin_amdgcn_mfma_f32_16x16x32_bf16(ap[mt], bv[nt], oacc[mt][hd*2+nt], 0, 0, 0);
      __builtin_amdgcn_s_setprio(0);
    }
  }

  __syncthreads();   // done with h (shf) & slots -> sh_o row-major o, xsh x-stash

  #pragma unroll
  for (int j=0;j<4;++j){
    const int col = wv*64 + j*16 + rowa;
    #pragma unroll
    for (int mt=0;mt<4;++mt)
      #pragma unroll
      for (int i=0;i<4;++i)
        sh_o[(mt*16 + kg*4 + i)*LDH + col] = f2bf(oacc[mt][j][i]);
  }
  {
    const int cbeg = wv*64;
    #pragma unroll
    for (int q=0;q<8;++q){
      bf16x8 pk;
      #pragma unroll
      for (int e=0;e<4;++e){
        const unsigned w = xpk[q*4+e];
        pk[2*e]   = (short)(w & 0xffffu);
        pk[2*e+1] = (short)(w >> 16);
      }
      *(bf16x8*)&xsh[ln*LDH + cbeg + q*8] = pk;
    }
  }
  __syncthreads();

  // ---- out-proj SWAPPED: D'[ch][tok] = wout x o^T; + bias + x residual(LDS) -> win2T ----
  {
    f32x4 acc[4][4];
    #pragma unroll
    for (int c0=0;c0<4;++c0)
      #pragma unroll
      for (int t0=0;t0<4;++t0)
        acc[c0][t0] = (f32x4){0.f,0.f,0.f,0.f};
    for (int kt=0; kt<8; ++kt){
      bf16x8 aw[4], bo[4];
      #pragma unroll
      for (int c0=0;c0<4;++c0)
        aw[c0] = WF(wout, wv*4 + c0, 8, kt, ln);
      #pragma unroll
      for (int t0=0;t0<4;++t0)
        bo[t0] = *(const bf16x8*)&sh_o[(t0*16+rowa)*LDH + kt*32 + kg*8];
      #pragma unroll
      for (int c0=0;c0<4;++c0)
        #pragma unroll
        for (int t0=0;t0<4;++t0)
          acc[c0][t0] = __builtin_amdgcn_mfma_f32_16x16x32_bf16(aw[c0], bo[t0], acc[c0][t0], 0, 0, 0);
    }
    #pragma unroll
    for (int c0=0;c0<4;++c0){
      #pragma unroll
      for (int i=0;i<4;++i){
        const int ch = wv*64 + c0*16 + kg*4 + i;
        const float bias = outb[ch];
        #pragma unroll
        for (int t0=0;t0<4;++t0){
          const int tok = t0*16 + rowa;
          const float res = bf2f(xsh[tok*LDH + ch]);
          win2T[(wi<<14) + ch*64 + tok] = f2bf(acc[c0][t0][i] + bias + res);
        }
      }
    }
  }
}

// ---------------- kernel 2: LN2 + half-chunk pipelined MLP (dbuf Mf, trimmed prefetch) ----
// LDS (51200 B): Yf 32768 | Mf 2 x 8192 | red 2048. Target 3 waves/SIMD:
// steady-state unified regs ~ acc2(64A)+acc1(16A)+w1c[4](16V)+w2c[8](32V)+misc <= 170.
#define K2_OFF_M   32768
#define K2_OFF_RED 49152
#define K2_SMEM    51200

// G1 step with preloaded w1 frag: acc1[ct] += aw x Y-token-tile(ct)
__device__ __forceinline__ void g1h_pre(const bf16x8 aw, const short* Yf,
                                        int kt, int ln, f32x4 acc1[4]){
  bf16x8 bh[4];
  #pragma unroll
  for (int ct=0;ct<4;++ct)
    bh[ct] = FRAG(Yf, ct, 8, kt, ln);
  #pragma unroll
  for (int ct=0;ct<4;++ct)
    acc1[ct] = __builtin_amdgcn_mfma_f32_16x16x32_bf16(aw, bh[ct], acc1[ct], 0, 0, 0);
}

// G2 step with preloaded w2 frags: acc2[c0][t0] += w2c[c0] x M frag
__device__ __forceinline__ void g2h_pre(const short* Mfb, const bf16x8* w2c4,
                                        int kt2, int ln, f32x4 acc2[4][4]){
  bf16x8 bm[4];
  #pragma unroll
  for (int t0=0;t0<4;++t0)
    bm[t0] = FRAG(Mfb, t0, 2, kt2, ln);
  #pragma unroll
  for (int c0=0;c0<4;++c0)
    #pragma unroll
    for (int t0=0;t0<4;++t0)
      acc2[c0][t0] = __builtin_amdgcn_mfma_f32_16x16x32_bf16(w2c4[c0], bm[t0], acc2[c0][t0], 0, 0, 0);
}

// GELU(acc1)+bias -> Mf frag-packed b64 writes (tanh-form gelu)
__device__ __forceinline__ void gstore_h(short* Mfb, const float* __restrict__ b1,
                                         int c, int wv, int rowa, int kg,
                                         const f32x4 acc1[4]){
  const int hidb = c*64 + wv*16 + kg*4;
  const f32x4 b1v = *(const f32x4*)&b1[hidb];
  #pragma unroll
  for (int ct=0;ct<4;++ct){
    bf16x4 st;
    #pragma unroll
    for (int i=0;i<4;++i)
      st[i] = f2bf(gelu_f(acc1[ct][i] + b1v[i]));
    *(bf16x4*)&Mfb[(((ct*2 + (wv>>1))*64) + ((wv&1)*2 + (kg>>1))*16 + rowa)*8 + (kg&1)*4] = st;
  }
}

__global__ __launch_bounds__(256, 3)
void swin_mlp_kernel(const short* __restrict__ win2T,
                     const float* __restrict__ ln2w, const float* __restrict__ ln2b,
                     const float* __restrict__ b1,   const float* __restrict__ b2,
                     const short* __restrict__ w1,   const short* __restrict__ w2,
                     float* __restrict__ out)
{
  __shared__ char smem[K2_SMEM];
  short* Yf  = (short*)smem;
  short* Mf0 = (short*)(smem + K2_OFF_M);
  short* Mf1 = Mf0 + 4096;
  float* red_s  = (float*)(smem + K2_OFF_RED);
  float* red_q2 = red_s + 256;

  const int tid = threadIdx.x;
  const int wv  = tid >> 6;
  const int ln  = tid & 63;
  const int rowa = ln & 15;
  const int kg   = ln >> 4;

  const int bid = blockIdx.x;
  const int wi  = ((bid & 7) << 8) | (bid >> 3);   // XCD swizzle
  const int wb = wi << 14;

  // ---- LN2 from win2T (coalesced rows) -> Yf frag-packed ----
  {
    float vals[64];
    float s = 0.f, sq = 0.f;
    const int cbeg = wv*64;
    #pragma unroll
    for (int j=0;j<64;++j){
      float v = bf2f(win2T[wb + (cbeg + j)*64 + ln]);
      vals[j] = v; s += v; sq += v*v;
    }
    red_s[cbeg + ln]  = s;
    red_q2[cbeg + ln] = sq;
    __syncthreads();
    float sum = red_s[ln] + red_s[64+ln] + red_s[128+ln] + red_s[192+ln];
    float ssq = red_q2[ln] + red_q2[64+ln] + red_q2[128+ln] + red_q2[192+ln];
    float mean = sum * 0.00390625f;
    float var  = ssq * 0.00390625f - mean*mean;
    float rstd = rsqrtf(var + 1e-5f);
    const int ttile = ln >> 4;
    #pragma unroll
    for (int kl=0;kl<2;++kl){
      const int kt = wv*2 + kl;
      #pragma unroll
      for (int kgw=0;kgw<4;++kgw){
        bf16x8 pkv;
        #pragma unroll
        for (int e=0;e<8;++e){
          const int j = kl*32 + kgw*8 + e;
          const int c = cbeg + j;
          pkv[e] = f2bf((vals[j] - mean) * rstd * ln2w[c] + ln2b[c]);
        }
        *(bf16x8*)&Yf[(((ttile*8 + kt)*64) + kgw*16 + (ln & 15))*8] = pkv;
      }
    }
  }
  __syncthreads();

  // ---- half-chunk pipeline with trimmed register prefetch ----
  f32x4 acc2[4][4];
  #pragma unroll
  for (int c0=0;c0<4;++c0)
    #pragma unroll
    for (int t0=0;t0<4;++t0)
      acc2[c0][t0] = (f32x4){0.f,0.f,0.f,0.f};

  // prologue: w1 frags kt0-3 for chunk 0, G1(0) (kt4-7 loaded inline)
  bf16x8 w1c[4];
  #pragma unroll
  for (int kt=0;kt<4;++kt) w1c[kt] = WF(w1, 0*4 + wv, 8, kt, ln);
  f32x4 acc1[4];
  #pragma unroll
  for (int ct=0;ct<4;++ct) acc1[ct] = (f32x4){0.f,0.f,0.f,0.f};
  #pragma unroll
  for (int kt=0;kt<4;++kt) g1h_pre(w1c[kt], Yf, kt, ln, acc1);
  #pragma unroll
  for (int kt=4;kt<8;++kt) g1h_pre(WF(w1, 0*4 + wv, 8, kt, ln), Yf, kt, ln, acc1);

  #pragma unroll
  for (int c = 0; c < 16; ++c){
    short* cur = (c & 1) ? Mf1 : Mf0;
    gstore_h(cur, b1, c, wv, rowa, kg, acc1);

    // issue THIS chunk's w2 frags + NEXT chunk's first-half w1 frags before the barrier
    bf16x8 w2c[8];
    #pragma unroll
    for (int j=0;j<8;++j)
      w2c[j] = WF(w2, wv*4 + (j & 3), 32, c*2 + (j >> 2), ln);
    if (c < 15){
      #pragma unroll
      for (int kt=0;kt<4;++kt)
        w1c[kt] = WF(w1, (c+1)*4 + wv, 8, kt, ln);
    }
    __syncthreads();   // Mf(c) published

    if (c < 15){
      f32x4 acc1n[4];
      #pragma unroll
      for (int ct=0;ct<4;++ct) acc1n[ct] = (f32x4){0.f,0.f,0.f,0.f};
      #pragma unroll
      for (int kt=0;kt<4;++kt) g1h_pre(w1c[kt], Yf, kt, ln, acc1n);
      g2h_pre(cur, &w2c[0], 0, ln, acc2);
      #pragma unroll
      for (int kt=4;kt<8;++kt)
        g1h_pre(WF(w1, (c+1)*4 + wv, 8, kt, ln), Yf, kt, ln, acc1n);  // inline loads, overlap G2/G1
      g2h_pre(cur, &w2c[4], 1, ln, acc2);
      #pragma unroll
      for (int ct=0;ct<4;++ct) acc1[ct] = acc1n[ct];
    } else {
      g2h_pre(cur, &w2c[0], 0, ln, acc2);
      g2h_pre(cur, &w2c[4], 1, ln, acc2);
    }
  }

  // ---- epilogue: D'[ch][tok]: + b2 + win2T residual (coalesced), coalesced NCHW store ----
  const int b  = wi >> 8;
  const int wh = (wi >> 4) & 15;
  const int ww = wi & 15;
  #pragma unroll
  for (int c0=0;c0<4;++c0){
    #pragma unroll
    for (int i=0;i<4;++i){
      const int ch = wv*64 + c0*16 + kg*4 + i;
      const float bias = b2[ch];
      #pragma unroll
      for (int t0=0;t0<4;++t0){
        const int tok = t0*16 + rowa;
        float v = acc2[c0][t0][i] + bias + bf2f(win2T[wb + ch*64 + tok]);
        const int r = tok >> 3, cw = tok & 7;
        const int hh = (wh*8 + r + 4) & 127;
        const int wcc = (ww*8 + cw + 4) & 127;
        out[(((b<<8) + ch) << 14) + hh*128 + wcc] = v;
      }
    }
  }
}

// ---------------- launch ----------------
extern "C" void kernel_launch(void* const* d_in, const int* in_sizes, int n_in,
                              void* d_out, int out_size, void* d_ws, size_t ws_size,
                              hipStream_t stream) {
  (void)in_sizes; (void)n_in; (void)out_size; (void)ws_size;
  const float* x    = (const float*)d_in[0];
  const float* ln1w = (const float*)d_in[1];
  const float* ln1b = (const float*)d_in[2];
  const float* inw  = (const float*)d_in[3];
  const float* inb  = (const float*)d_in[4];
  const float* outw = (const float*)d_in[5];
  const float* outb = (const float*)d_in[6];
  const float* ln2w = (const float*)d_in[7];
  const float* ln2b = (const float*)d_in[8];
  const float* w1f  = (const float*)d_in[9];
  const float* b1   = (const float*)d_in[10];
  const float* w2f  = (const float*)d_in[11];
  const float* b2   = (const float*)d_in[12];
  float* out = (float*)d_out;

  short* ws    = (short*)d_ws;
  short* wqkv  = ws;            // 768*256   (frag-packed, KT=8)
  short* wout  = ws + 196608;   // 256*256   (frag-packed, KT=8)
  short* w1b   = ws + 262144;   // 1024*256  (frag-packed, KT=8)
  short* w2b   = ws + 524288;   // 256*1024  (frag-packed, KT=32)
  short* win2T = ws + 786432;   // 2048 x 256ch x 64tok bf16

  hipLaunchKernelGGL(wpack_kernel, dim3(96),  dim3(256), 0, stream, inw,  wqkv, 256);
  hipLaunchKernelGGL(wpack_kernel, dim3(32),  dim3(256), 0, stream, outw, wout, 256);
  hipLaunchKernelGGL(wpack_kernel, dim3(128), dim3(256), 0, stream, w1f,  w1b,  256);
  hipLaunchKernelGGL(wpack_kernel, dim3(128), dim3(256), 0, stream, w2f,  w2b,  1024);

  hipLaunchKernelGGL(swin_attn_kernel, dim3(2048), dim3(256), 0, stream,
                     x, ln1w, ln1b, inb, outb, wqkv, wout, win2T);
  hipLaunchKernelGGL(swin_mlp_kernel, dim3(2048), dim3(256), 0, stream,
                     win2T, ln2w, ln2b, b1, b2, w1b, w2b, out);
}

// Round 16
// 391.796 us; speedup vs baseline: 1.3811x; 1.0506x over previous
//
#include <hip/hip_runtime.h>
#include <math.h>

// Swin block: B=8, C=256, H=W=128, WS=8, SS=4, NH=8, dh=32
// Weights frag-packed: wf[((tile*KT+kt)*64+l)*8+e] = W[tile*16+(l&15)][kt*32+(l>>4)*8+e]
// attn: x read once (reg stash), XCD swizzle, frag-packed h.
// mlp: half-chunk pipeline, dbuf Mf, trimmed reg prefetch (3 waves/SIMD);
// r16: cheap rcp-GELU + gelu/pack hoisted into G2b's MFMA shadow (stv regs cross barrier).

#define LDH 264   // bf16 row stride for row-major [64][256] tiles (o, xsh)
#define LDS_S 40  // per-wave q/k slots [64][40]
#define LDVT 72   // vT [32][72]

typedef __attribute__((ext_vector_type(8))) short bf16x8;
typedef __attribute__((ext_vector_type(4))) short bf16x4;
typedef __attribute__((ext_vector_type(4))) float f32x4;

#define WF(wf, tile, KT, kt, ln) (*(const bf16x8*)&(wf)[((((tile)*(KT)) + (kt))*64 + (ln))*8])
// frag-packed LDS tile (4 token-tiles x KT k-steps): FRAG(base, ttile, KT, kt, lane)
#define FRAG(basep, ttile, KT, kt, l) (*(const bf16x8*)&(basep)[((((ttile)*(KT)) + (kt))*64 + (l))*8])

static __device__ __forceinline__ float bf2f(short s){
  union { unsigned u; float f; } cv;
  cv.u = ((unsigned)(unsigned short)s) << 16;
  return cv.f;
}
// native bf16 convert (RNE; clang lowers to v_cvt_pk_bf16_f32)
static __device__ __forceinline__ short f2bf(float f){
  __bf16 h = (__bf16)f;
  union { __bf16 b; short s; } cv; cv.b = h;
  return cv.s;
}
// tanh-form GELU via g = x*(1 - 1/(e+1)), e = exp(2*sqrt(2/pi)*(x+0.044715x^3)).
// NaN-safe: e->inf => g=x; e->0 => g=0 (x finite). ~8 VALU ops, v_rcp not div-seq.
static __device__ __forceinline__ float gelu_f(float x){
  const float x2 = x * x;
  const float u  = x * fmaf(0.0713537014f, x2, 1.5957691216f);  // 2a*0.044715, 2a
  const float e  = __expf(u);
  const float r  = __builtin_amdgcn_rcpf(e + 1.f);
  return x * (1.f - r);
}

// ---------------- K0: fp32 -> bf16 fragment-order repack ----------------
__global__ void wpack_kernel(const float* __restrict__ src, short* __restrict__ dst,
                             int K){
  const int t8 = blockIdx.x * 256 + threadIdx.x;
  const int e0 = t8 * 8;
  const int l   = (e0 >> 3) & 63;
  const int blk = e0 >> 9;
  const int KT  = K >> 5;
  const int kt   = blk % KT;
  const int tile = blk / KT;
  const int row = tile*16 + (l & 15);
  const int kb  = kt*32 + (l >> 4)*8;
  const float* s = src + row*K + kb;
  bf16x8 o;
  #pragma unroll
  for (int e=0;e<8;++e) o[e] = f2bf(s[e]);
  *(bf16x8*)&dst[e0] = o;
}

// ---------------- kernel 1: LN1 + QKV + attention + out-proj(swapped) -> win2T ----------------
#define K1_OFF_WV  33792
#define K1_OFF_RED 74752
#define K1_SMEM    76800

__global__ __launch_bounds__(256, 2)
void swin_attn_kernel(const float* __restrict__ x,
                      const float* __restrict__ ln1w, const float* __restrict__ ln1b,
                      const float* __restrict__ inb,  const float* __restrict__ outb,
                      const short* __restrict__ wqkv, const short* __restrict__ wout,
                      short* __restrict__ win2T)
{
  __shared__ char smem[K1_SMEM];
  short* shf    = (short*)smem;                 // h frag-packed (32768 B), then o row-major [64][264]
  short* sh_o   = (short*)smem;
  short* xsh    = (short*)(smem + K1_OFF_WV);   // x bf16 stash row-major (post-attention)
  float* red_s  = (float*)(smem + K1_OFF_RED);
  float* red_q2 = red_s + 256;

  const int tid = threadIdx.x;
  const int wv  = tid >> 6;
  const int ln  = tid & 63;
  const int rowa = ln & 15;
  const int kg   = ln >> 4;

  short* slotA = (short*)(smem + K1_OFF_WV) + wv*5120;
  short* slotB = slotA + 2560;

  const int bid = blockIdx.x;
  const int wi  = ((bid & 7) << 8) | (bid >> 3);   // XCD swizzle (2048%8==0, bijective)
  const int b  = wi >> 8;
  const int wh = (wi >> 4) & 15;
  const int ww = wi & 15;

  const int hh = (wh*8 + (ln >> 3) + 4) & 127;
  const int wc = (ww*8 + (ln & 7) + 4) & 127;
  const int offhw = hh*128 + wc;
  const int xbase = b << 22;

  unsigned xpk[32];
  {
    const int cbeg = wv*64;
    float vals[64];
    float s = 0.f, sq = 0.f;
    #pragma unroll
    for (int j = 0; j < 64; ++j){
      float v = x[xbase + ((cbeg + j) << 14) + offhw];
      vals[j] = v; s += v; sq += v*v;
    }
    #pragma unroll
    for (int p = 0; p < 32; ++p){
      const unsigned lo = (unsigned)(unsigned short)f2bf(vals[2*p]);
      const unsigned hi = (unsigned)(unsigned short)f2bf(vals[2*p+1]);
      xpk[p] = lo | (hi << 16);
    }
    red_s[cbeg + ln]  = s;
    red_q2[cbeg + ln] = sq;
    __syncthreads();
    float sum = red_s[ln] + red_s[64+ln] + red_s[128+ln] + red_s[192+ln];
    float ssq = red_q2[ln] + red_q2[64+ln] + red_q2[128+ln] + red_q2[192+ln];
    float mean = sum * 0.00390625f;
    float var  = ssq * 0.00390625f - mean*mean;
    float rstd = rsqrtf(var + 1e-5f);
    // h frag-packed write
    const int ttile = ln >> 4;
    #pragma unroll
    for (int kl=0;kl<2;++kl){
      const int kt = wv*2 + kl;
      #pragma unroll
      for (int kgw=0;kgw<4;++kgw){
        bf16x8 pkv;
        #pragma unroll
        for (int e=0;e<8;++e){
          const int j = kl*32 + kgw*8 + e;
          const int c = cbeg + j;
          pkv[e] = f2bf((vals[j] - mean) * rstd * ln1w[c] + ln1b[c]);
        }
        *(bf16x8*)&shf[(((ttile*8 + kt)*64) + kgw*16 + (ln & 15))*8] = pkv;
      }
    }
  }
  __syncthreads();

  const float scale = 0.1767766952966369f;
  f32x4 oacc[4][4];
  #pragma unroll
  for (int mt=0;mt<4;++mt)
    #pragma unroll
    for (int j=0;j<4;++j)
      oacc[mt][j] = (f32x4){0.f,0.f,0.f,0.f};

  #pragma unroll
  for (int hd = 0; hd < 2; ++hd){
    const int hc = (2*wv + hd) * 32;
    const int tq = (2*wv + hd) * 2;

    // ---- q + k fused (shared A-frags from frag-packed h) ----
    {
      f32x4 aq[4][2], ak[4][2];
      #pragma unroll
      for (int mt=0;mt<4;++mt){
        aq[mt][0]=(f32x4){0,0,0,0}; aq[mt][1]=(f32x4){0,0,0,0};
        ak[mt][0]=(f32x4){0,0,0,0}; ak[mt][1]=(f32x4){0,0,0,0};
      }
      #pragma unroll
      for (int kt=0;kt<8;++kt){
        bf16x8 av[4], bq[2], bk[2];
        #pragma unroll
        for (int mt=0;mt<4;++mt)
          av[mt] = FRAG(shf, mt, 8, kt, ln);
        #pragma unroll
        for (int nt=0;nt<2;++nt){
          bq[nt] = WF(wqkv, tq + nt,      8, kt, ln);
          bk[nt] = WF(wqkv, 16 + tq + nt, 8, kt, ln);
        }
        #pragma unroll
        for (int mt=0;mt<4;++mt)
          #pragma unroll
          for (int nt=0;nt<2;++nt){
            aq[mt][nt] = __builtin_amdgcn_mfma_f32_16x16x32_bf16(av[mt], bq[nt], aq[mt][nt], 0, 0, 0);
            ak[mt][nt] = __builtin_amdgcn_mfma_f32_16x16x32_bf16(av[mt], bk[nt], ak[mt][nt], 0, 0, 0);
          }
      }
      #pragma unroll
      for (int nt=0;nt<2;++nt){
        const float biasq = inb[hc + nt*16 + rowa];
        const float biask = inb[256 + hc + nt*16 + rowa];
        #pragma unroll
        for (int mt=0;mt<4;++mt)
          #pragma unroll
          for (int i=0;i<4;++i){
            slotA[(mt*16 + kg*4 + i)*LDS_S + nt*16 + rowa] = f2bf(aq[mt][nt][i] + biasq);
            slotB[(mt*16 + kg*4 + i)*LDS_S + nt*16 + rowa] = f2bf(ak[mt][nt][i] + biask);
          }
      }
    }

    // ---- S = q @ k^T ----
    f32x4 sacc[4][4];
    #pragma unroll
    for (int mt=0;mt<4;++mt)
      #pragma unroll
      for (int nt=0;nt<4;++nt)
        sacc[mt][nt] = (f32x4){0.f,0.f,0.f,0.f};
    {
      bf16x8 aq[4], bk[4];
      #pragma unroll
      for (int mt=0;mt<4;++mt)
        aq[mt] = *(const bf16x8*)&slotA[(mt*16+rowa)*LDS_S + kg*8];
      #pragma unroll
      for (int nt=0;nt<4;++nt)
        bk[nt] = *(const bf16x8*)&slotB[(nt*16+rowa)*LDS_S + kg*8];
      __builtin_amdgcn_s_setprio(1);
      #pragma unroll
      for (int mt=0;mt<4;++mt)
        #pragma unroll
        for (int nt=0;nt<4;++nt)
          sacc[mt][nt] = __builtin_amdgcn_mfma_f32_16x16x32_bf16(aq[mt], bk[nt], sacc[mt][nt], 0, 0, 0);
      __builtin_amdgcn_s_setprio(0);
    }

    // ---- v -> vT [32][72] in slotB ----
    {
      f32x4 accv[4][2];
      #pragma unroll
      for (int mt=0;mt<4;++mt){ accv[mt][0]=(f32x4){0,0,0,0}; accv[mt][1]=(f32x4){0,0,0,0}; }
      #pragma unroll
      for (int kt=0;kt<8;++kt){
        bf16x8 av[4], bw[2];
        #pragma unroll
        for (int mt=0;mt<4;++mt)
          av[mt] = FRAG(shf, mt, 8, kt, ln);
        #pragma unroll
        for (int nt=0;nt<2;++nt)
          bw[nt] = WF(wqkv, 32 + tq + nt, 8, kt, ln);
        #pragma unroll
        for (int mt=0;mt<4;++mt)
          #pragma unroll
          for (int nt=0;nt<2;++nt)
            accv[mt][nt] = __builtin_amdgcn_mfma_f32_16x16x32_bf16(av[mt], bw[nt], accv[mt][nt], 0, 0, 0);
      }
      #pragma unroll
      for (int nt=0;nt<2;++nt){
        const float bias = inb[512 + hc + nt*16 + rowa];
        #pragma unroll
        for (int mt=0;mt<4;++mt)
          #pragma unroll
          for (int i=0;i<4;++i)
            slotB[(nt*16 + rowa)*LDVT + mt*16 + kg*4 + i] = f2bf(accv[mt][nt][i] + bias);
      }
    }

    // ---- softmax ----
    #pragma unroll
    for (int mt=0;mt<4;++mt){
      #pragma unroll
      for (int i=0;i<4;++i){
        float v0 = sacc[mt][0][i]*scale;
        float v1 = sacc[mt][1][i]*scale;
        float v2 = sacc[mt][2][i]*scale;
        float v3 = sacc[mt][3][i]*scale;
        float mx = fmaxf(fmaxf(v0,v1), fmaxf(v2,v3));
        #pragma unroll
        for (int d=1; d<16; d<<=1) mx = fmaxf(mx, __shfl_xor(mx, d, 64));
        v0 = __expf(v0-mx); v1 = __expf(v1-mx); v2 = __expf(v2-mx); v3 = __expf(v3-mx);
        float sm = v0+v1+v2+v3;
        #pragma unroll
        for (int d=1; d<16; d<<=1) sm += __shfl_xor(sm, d, 64);
        const float inv = 1.f / sm;
        sacc[mt][0][i] = v0*inv; sacc[mt][1][i] = v1*inv;
        sacc[mt][2][i] = v2*inv; sacc[mt][3][i] = v3*inv;
      }
    }

    // ---- PV in two kv-chunks of 32, P through slotA ----
    #pragma unroll
    for (int ck=0; ck<2; ++ck){
      #pragma unroll
      for (int ntl=0; ntl<2; ++ntl)
        #pragma unroll
        for (int mt=0;mt<4;++mt)
          #pragma unroll
          for (int i=0;i<4;++i)
            slotA[(mt*16 + kg*4 + i)*LDS_S + ntl*16 + rowa] = f2bf(sacc[mt][2*ck+ntl][i]);
      bf16x8 ap[4], bv[2];
      #pragma unroll
      for (int mt=0;mt<4;++mt)
        ap[mt] = *(const bf16x8*)&slotA[(mt*16+rowa)*LDS_S + kg*8];
      #pragma unroll
      for (int nt=0;nt<2;++nt)
        bv[nt] = *(const bf16x8*)&slotB[(nt*16+rowa)*LDVT + ck*32 + kg*8];
      __builtin_amdgcn_s_setprio(1);
      #pragma unroll
      for (int mt=0;mt<4;++mt)
        #pragma unroll
        for (int nt=0;nt<2;++nt)
          oacc[mt][hd*2+nt] = __builtin_amdgcn_mfma_f32_16x16x32_bf16(ap[mt], bv[nt], oacc[mt][hd*2+nt], 0, 0, 0);
      __builtin_amdgcn_s_setprio(0);
    }
  }

  __syncthreads();   // done with h (shf) & slots -> sh_o row-major o, xsh x-stash

  #pragma unroll
  for (int j=0;j<4;++j){
    const int col = wv*64 + j*16 + rowa;
    #pragma unroll
    for (int mt=0;mt<4;++mt)
      #pragma unroll
      for (int i=0;i<4;++i)
        sh_o[(mt*16 + kg*4 + i)*LDH + col] = f2bf(oacc[mt][j][i]);
  }
  {
    const int cbeg = wv*64;
    #pragma unroll
    for (int q=0;q<8;++q){
      bf16x8 pk;
      #pragma unroll
      for (int e=0;e<4;++e){
        const unsigned w = xpk[q*4+e];
        pk[2*e]   = (short)(w & 0xffffu);
        pk[2*e+1] = (short)(w >> 16);
      }
      *(bf16x8*)&xsh[ln*LDH + cbeg + q*8] = pk;
    }
  }
  __syncthreads();

  // ---- out-proj SWAPPED: D'[ch][tok] = wout x o^T; + bias + x residual(LDS) -> win2T ----
  {
    f32x4 acc[4][4];
    #pragma unroll
    for (int c0=0;c0<4;++c0)
      #pragma unroll
      for (int t0=0;t0<4;++t0)
        acc[c0][t0] = (f32x4){0.f,0.f,0.f,0.f};
    for (int kt=0; kt<8; ++kt){
      bf16x8 aw[4], bo[4];
      #pragma unroll
      for (int c0=0;c0<4;++c0)
        aw[c0] = WF(wout, wv*4 + c0, 8, kt, ln);
      #pragma unroll
      for (int t0=0;t0<4;++t0)
        bo[t0] = *(const bf16x8*)&sh_o[(t0*16+rowa)*LDH + kt*32 + kg*8];
      #pragma unroll
      for (int c0=0;c0<4;++c0)
        #pragma unroll
        for (int t0=0;t0<4;++t0)
          acc[c0][t0] = __builtin_amdgcn_mfma_f32_16x16x32_bf16(aw[c0], bo[t0], acc[c0][t0], 0, 0, 0);
    }
    #pragma unroll
    for (int c0=0;c0<4;++c0){
      #pragma unroll
      for (int i=0;i<4;++i){
        const int ch = wv*64 + c0*16 + kg*4 + i;
        const float bias = outb[ch];
        #pragma unroll
        for (int t0=0;t0<4;++t0){
          const int tok = t0*16 + rowa;
          const float res = bf2f(xsh[tok*LDH + ch]);
          win2T[(wi<<14) + ch*64 + tok] = f2bf(acc[c0][t0][i] + bias + res);
        }
      }
    }
  }
}

// ---------------- kernel 2: LN2 + half-chunk pipelined MLP (dbuf Mf, hoisted gelu) ----
// LDS (51200 B): Yf 32768 | Mf 2 x 8192 | red 2048. 3 waves/SIMD.
#define K2_OFF_M   32768
#define K2_OFF_RED 49152
#define K2_SMEM    51200

// G1 step with preloaded w1 frag: acc1[ct] += aw x Y-token-tile(ct)
__device__ __forceinline__ void g1h_pre(const bf16x8 aw, const short* Yf,
                                        int kt, int ln, f32x4 acc1[4]){
  bf16x8 bh[4];
  #pragma unroll
  for (int ct=0;ct<4;++ct)
    bh[ct] = FRAG(Yf, ct, 8, kt, ln);
  #pragma unroll
  for (int ct=0;ct<4;++ct)
    acc1[ct] = __builtin_amdgcn_mfma_f32_16x16x32_bf16(aw, bh[ct], acc1[ct], 0, 0, 0);
}

// G2 step with preloaded w2 frags: acc2[c0][t0] += w2c[c0] x M frag
__device__ __forceinline__ void g2h_pre(const short* Mfb, const bf16x8* w2c4,
                                        int kt2, int ln, f32x4 acc2[4][4]){
  bf16x8 bm[4];
  #pragma unroll
  for (int t0=0;t0<4;++t0)
    bm[t0] = FRAG(Mfb, t0, 2, kt2, ln);
  #pragma unroll
  for (int c0=0;c0<4;++c0)
    #pragma unroll
    for (int t0=0;t0<4;++t0)
      acc2[c0][t0] = __builtin_amdgcn_mfma_f32_16x16x32_bf16(w2c4[c0], bm[t0], acc2[c0][t0], 0, 0, 0);
}

// gelu+bias+pack acc1 -> stv (VALU; scheduled to overlap MFMA)
__device__ __forceinline__ void gelu_pack(const float* __restrict__ b1p,
                                          const f32x4 acc1[4], bf16x4 stv[4]){
  const f32x4 b1v = *(const f32x4*)b1p;
  #pragma unroll
  for (int ct=0;ct<4;++ct){
    #pragma unroll
    for (int i=0;i<4;++i)
      stv[ct][i] = f2bf(gelu_f(acc1[ct][i] + b1v[i]));
  }
}

// store-only: stv -> Mf frag-packed b64 writes
__device__ __forceinline__ void st_stv(short* Mfb, int wv, int rowa, int kg,
                                       const bf16x4 stv[4]){
  #pragma unroll
  for (int ct=0;ct<4;++ct)
    *(bf16x4*)&Mfb[(((ct*2 + (wv>>1))*64) + ((wv&1)*2 + (kg>>1))*16 + rowa)*8 + (kg&1)*4] = stv[ct];
}

__global__ __launch_bounds__(256, 3)
void swin_mlp_kernel(const short* __restrict__ win2T,
                     const float* __restrict__ ln2w, const float* __restrict__ ln2b,
                     const float* __restrict__ b1,   const float* __restrict__ b2,
                     const short* __restrict__ w1,   const short* __restrict__ w2,
                     float* __restrict__ out)
{
  __shared__ char smem[K2_SMEM];
  short* Yf  = (short*)smem;
  short* Mf0 = (short*)(smem + K2_OFF_M);
  short* Mf1 = Mf0 + 4096;
  float* red_s  = (float*)(smem + K2_OFF_RED);
  float* red_q2 = red_s + 256;

  const int tid = threadIdx.x;
  const int wv  = tid >> 6;
  const int ln  = tid & 63;
  const int rowa = ln & 15;
  const int kg   = ln >> 4;

  const int bid = blockIdx.x;
  const int wi  = ((bid & 7) << 8) | (bid >> 3);   // XCD swizzle
  const int wb = wi << 14;

  // ---- LN2 from win2T (coalesced rows) -> Yf frag-packed ----
  {
    float vals[64];
    float s = 0.f, sq = 0.f;
    const int cbeg = wv*64;
    #pragma unroll
    for (int j=0;j<64;++j){
      float v = bf2f(win2T[wb + (cbeg + j)*64 + ln]);
      vals[j] = v; s += v; sq += v*v;
    }
    red_s[cbeg + ln]  = s;
    red_q2[cbeg + ln] = sq;
    __syncthreads();
    float sum = red_s[ln] + red_s[64+ln] + red_s[128+ln] + red_s[192+ln];
    float ssq = red_q2[ln] + red_q2[64+ln] + red_q2[128+ln] + red_q2[192+ln];
    float mean = sum * 0.00390625f;
    float var  = ssq * 0.00390625f - mean*mean;
    float rstd = rsqrtf(var + 1e-5f);
    const int ttile = ln >> 4;
    #pragma unroll
    for (int kl=0;kl<2;++kl){
      const int kt = wv*2 + kl;
      #pragma unroll
      for (int kgw=0;kgw<4;++kgw){
        bf16x8 pkv;
        #pragma unroll
        for (int e=0;e<8;++e){
          const int j = kl*32 + kgw*8 + e;
          const int c = cbeg + j;
          pkv[e] = f2bf((vals[j] - mean) * rstd * ln2w[c] + ln2b[c]);
        }
        *(bf16x8*)&Yf[(((ttile*8 + kt)*64) + kgw*16 + (ln & 15))*8] = pkv;
      }
    }
  }
  __syncthreads();

  // ---- half-chunk pipeline; gelu+pack hoisted into G2b's MFMA shadow ----
  f32x4 acc2[4][4];
  #pragma unroll
  for (int c0=0;c0<4;++c0)
    #pragma unroll
    for (int t0=0;t0<4;++t0)
      acc2[c0][t0] = (f32x4){0.f,0.f,0.f,0.f};

  bf16x4 stv[4];   // packed gelu for the chunk to be stored at next loop top
  {
    f32x4 acc1[4];
    #pragma unroll
    for (int ct=0;ct<4;++ct) acc1[ct] = (f32x4){0.f,0.f,0.f,0.f};
    #pragma unroll
    for (int kt=0;kt<8;++kt)
      g1h_pre(WF(w1, 0*4 + wv, 8, kt, ln), Yf, kt, ln, acc1);
    gelu_pack(&b1[wv*16 + kg*4], acc1, stv);
  }

  bf16x8 w1c[4];
  #pragma unroll
  for (int c = 0; c < 16; ++c){
    short* cur = (c & 1) ? Mf1 : Mf0;
    st_stv(cur, wv, rowa, kg, stv);

    // issue THIS chunk's w2 frags + NEXT chunk's first-half w1 frags before the barrier
    bf16x8 w2c[8];
    #pragma unroll
    for (int j=0;j<8;++j)
      w2c[j] = WF(w2, wv*4 + (j & 3), 32, c*2 + (j >> 2), ln);
    if (c < 15){
      #pragma unroll
      for (int kt=0;kt<4;++kt)
        w1c[kt] = WF(w1, (c+1)*4 + wv, 8, kt, ln);
    }
    __syncthreads();   // Mf(c) published

    if (c < 15){
      f32x4 acc1n[4];
      #pragma unroll
      for (int ct=0;ct<4;++ct) acc1n[ct] = (f32x4){0.f,0.f,0.f,0.f};
      #pragma unroll
      for (int kt=0;kt<4;++kt) g1h_pre(w1c[kt], Yf, kt, ln, acc1n);
      g2h_pre(cur, &w2c[0], 0, ln, acc2);
      #pragma unroll
      for (int kt=4;kt<8;++kt)
        g1h_pre(WF(w1, (c+1)*4 + wv, 8, kt, ln), Yf, kt, ln, acc1n);  // inline loads
      gelu_pack(&b1[(c+1)*64 + wv*16 + kg*4], acc1n, stv);  // VALU under G2b's MFMAs
      g2h_pre(cur, &w2c[4], 1, ln, acc2);
    } else {
      g2h_pre(cur, &w2c[0], 0, ln, acc2);
      g2h_pre(cur, &w2c[4], 1, ln, acc2);
    }
  }

  // ---- epilogue: D'[ch][tok]: + b2 + win2T residual (coalesced), coalesced NCHW store ----
  const int b  = wi >> 8;
  const int wh = (wi >> 4) & 15;
  const int ww = wi & 15;
  #pragma unroll
  for (int c0=0;c0<4;++c0){
    #pragma unroll
    for (int i=0;i<4;++i){
      const int ch = wv*64 + c0*16 + kg*4 + i;
      const float bias = b2[ch];
      #pragma unroll
      for (int t0=0;t0<4;++t0){
        const int tok = t0*16 + rowa;
        float v = acc2[c0][t0][i] + bias + bf2f(win2T[wb + ch*64 + tok]);
        const int r = tok >> 3, cw = tok & 7;
        const int hh = (wh*8 + r + 4) & 127;
        const int wcc = (ww*8 + cw + 4) & 127;
        out[(((b<<8) + ch) << 14) + hh*128 + wcc] = v;
      }
    }
  }
}

// ---------------- launch ----------------
extern "C" void kernel_launch(void* const* d_in, const int* in_sizes, int n_in,
                              void* d_out, int out_size, void* d_ws, size_t ws_size,
                              hipStream_t stream) {
  (void)in_sizes; (void)n_in; (void)out_size; (void)ws_size;
  const float* x    = (const float*)d_in[0];
  const float* ln1w = (const float*)d_in[1];
  const float* ln1b = (const float*)d_in[2];
  const float* inw  = (const float*)d_in[3];
  const float* inb  = (const float*)d_in[4];
  const float* outw = (const float*)d_in[5];
  const float* outb = (const float*)d_in[6];
  const float* ln2w = (const float*)d_in[7];
  const float* ln2b = (const float*)d_in[8];
  const float* w1f  = (const float*)d_in[9];
  const float* b1   = (const float*)d_in[10];
  const float* w2f  = (const float*)d_in[11];
  const float* b2   = (const float*)d_in[12];
  float* out = (float*)d_out;

  short* ws    = (short*)d_ws;
  short* wqkv  = ws;            // 768*256   (frag-packed, KT=8)
  short* wout  = ws + 196608;   // 256*256   (frag-packed, KT=8)
  short* w1b   = ws + 262144;   // 1024*256  (frag-packed, KT=8)
  short* w2b   = ws + 524288;   // 256*1024  (frag-packed, KT=32)
  short* win2T = ws + 786432;   // 2048 x 256ch x 64tok bf16

  hipLaunchKernelGGL(wpack_kernel, dim3(96),  dim3(256), 0, stream, inw,  wqkv, 256);
  hipLaunchKernelGGL(wpack_kernel, dim3(32),  dim3(256), 0, stream, outw, wout, 256);
  hipLaunchKernelGGL(wpack_kernel, dim3(128), dim3(256), 0, stream, w1f,  w1b,  256);
  hipLaunchKernelGGL(wpack_kernel, dim3(128), dim3(256), 0, stream, w2f,  w2b,  1024);

  hipLaunchKernelGGL(swin_attn_kernel, dim3(2048), dim3(256), 0, stream,
                     x, ln1w, ln1b, inb, outb, wqkv, wout, win2T);
  hipLaunchKernelGGL(swin_mlp_kernel, dim3(2048), dim3(256), 0, stream,
                     win2T, ln2w, ln2b, b1, b2, w1b, w2b, out);
}